// Round 1
// baseline (2503.952 us; speedup 1.0000x reference)
//
#include <hip/hip_runtime.h>

#define NB 32       // B
#define NT 512      // T
#define ND 2048     // D
#define NDM 256     // DM
#define NDI 512     // DI
#define NDS 16      // DS
#define NR 16       // R
#define NDC 4       // DC
#define NH 128      // H
#define NNC 8       // NC
#define NL 4        // L
#define NM (NB*NT)  // 16384 tokens

// ---------------------------------------------------------------------------
// masked time-instance-norm statistics: mean/rstd per (b,d)
// ---------------------------------------------------------------------------
__global__ __launch_bounds__(256) void tin_stats_k(
    const float* __restrict__ x, const int* __restrict__ lengths,
    float* __restrict__ mean, float* __restrict__ rstd)
{
    __shared__ float rs_[4][64];
    __shared__ float rq_[4][64];
    const int b = blockIdx.x >> 5;            // /32
    const int d0 = (blockIdx.x & 31) << 6;    // *64
    const int dl = threadIdx.x & 63;
    const int strip = threadIdx.x >> 6;       // 0..3
    const int len = lengths[b];
    const int d = d0 + dl;
    float s = 0.f, q = 0.f;
    for (int t = strip; t < len; t += 4) {
        float v = x[((size_t)(b*NT + t))*ND + d];
        s += v; q += v*v;
    }
    rs_[strip][dl] = s; rq_[strip][dl] = q;
    __syncthreads();
    if (threadIdx.x < 64) {
        float S = rs_[0][dl]+rs_[1][dl]+rs_[2][dl]+rs_[3][dl];
        float Q = rq_[0][dl]+rq_[1][dl]+rq_[2][dl]+rq_[3][dl];
        float inv = 1.f / (float)(len < 1 ? 1 : len);
        float mu = S * inv;
        float var = Q * inv - mu*mu;
        mean[b*ND + d] = mu;
        rstd[b*ND + d] = rsqrtf(var + 1e-5f);
    }
}

// ---------------------------------------------------------------------------
// GEMM: C[M,N] (op)= A[M,K] @ W[N,K]^T
// AMODE 0: plain A; 1: A = instnorm(x) (mean/rstd/gamma/beta/mask fused);
// AMODE 2: A = A * silu(A2)
// EPI 0: C = acc (+bias); EPI 1: C += rs*acc; EPI 2: C = tanh(acc+bias)
// ---------------------------------------------------------------------------
#define BM 128
#define BN 128
#define BK 16
#define LST 132   // padded LDS stride (float4-aligned)

template<int AMODE, int EPI>
__global__ __launch_bounds__(256) void gemm_k(
    const float* __restrict__ A, int lda,
    const float* __restrict__ A2, int lda2,
    const float* __restrict__ W,
    const float* __restrict__ bias,
    float* __restrict__ C,
    int M, int N, int K,
    const float* __restrict__ mean, const float* __restrict__ rstd,
    const float* __restrict__ gamma, const float* __restrict__ beta,
    const int* __restrict__ lengths,
    const float* __restrict__ rsp)
{
    __shared__ float As[BK][LST];
    __shared__ float Bs[BK][LST];
    const int tid = threadIdx.x;
    const int m0 = blockIdx.x * BM;
    const int n0 = blockIdx.y * BN;
    const int row = tid >> 1;         // 0..127
    const int kq  = (tid & 1) << 3;   // 0 or 8
    const int tx = tid & 15;
    const int ty = tid >> 4;
    const int gr = m0 + row;
    const int wr = n0 + row;
    const bool wv = (wr < N);
    int lenb = 0, tcur = 0, bb = 0;
    if (AMODE == 1) { bb = m0 / NT; lenb = lengths[bb]; tcur = gr - bb*NT; }

    float acc[8][8];
#pragma unroll
    for (int i = 0; i < 8; ++i)
#pragma unroll
        for (int j = 0; j < 8; ++j) acc[i][j] = 0.f;

    for (int k0 = 0; k0 < K; k0 += BK) {
        float4 a0, a1, w0, w1;
        const float* ap = A + (size_t)gr*lda + (k0 + kq);
        a0 = *(const float4*)ap;
        a1 = *(const float4*)(ap + 4);
        if (AMODE == 1) {
            if (tcur >= lenb) {
                a0 = make_float4(0.f,0.f,0.f,0.f); a1 = a0;
            } else {
                const int kb = bb*ND + k0 + kq;
                const int kg = k0 + kq;
                float4 mn0 = *(const float4*)(mean + kb);
                float4 mn1 = *(const float4*)(mean + kb + 4);
                float4 rr0 = *(const float4*)(rstd + kb);
                float4 rr1 = *(const float4*)(rstd + kb + 4);
                float4 g0 = *(const float4*)(gamma + kg);
                float4 g1 = *(const float4*)(gamma + kg + 4);
                float4 e0 = *(const float4*)(beta + kg);
                float4 e1 = *(const float4*)(beta + kg + 4);
                a0.x = (a0.x - mn0.x)*rr0.x*g0.x + e0.x;
                a0.y = (a0.y - mn0.y)*rr0.y*g0.y + e0.y;
                a0.z = (a0.z - mn0.z)*rr0.z*g0.z + e0.z;
                a0.w = (a0.w - mn0.w)*rr0.w*g0.w + e0.w;
                a1.x = (a1.x - mn1.x)*rr1.x*g1.x + e1.x;
                a1.y = (a1.y - mn1.y)*rr1.y*g1.y + e1.y;
                a1.z = (a1.z - mn1.z)*rr1.z*g1.z + e1.z;
                a1.w = (a1.w - mn1.w)*rr1.w*g1.w + e1.w;
            }
        } else if (AMODE == 2) {
            const float* zp = A2 + (size_t)gr*lda2 + (k0 + kq);
            float4 z0 = *(const float4*)zp;
            float4 z1 = *(const float4*)(zp + 4);
            a0.x *= z0.x / (1.f + __expf(-z0.x));
            a0.y *= z0.y / (1.f + __expf(-z0.y));
            a0.z *= z0.z / (1.f + __expf(-z0.z));
            a0.w *= z0.w / (1.f + __expf(-z0.w));
            a1.x *= z1.x / (1.f + __expf(-z1.x));
            a1.y *= z1.y / (1.f + __expf(-z1.y));
            a1.z *= z1.z / (1.f + __expf(-z1.z));
            a1.w *= z1.w / (1.f + __expf(-z1.w));
        }
        if (wv) {
            const float* wp = W + (size_t)wr*K + (k0 + kq);
            w0 = *(const float4*)wp;
            w1 = *(const float4*)(wp + 4);
        } else {
            w0 = make_float4(0.f,0.f,0.f,0.f); w1 = w0;
        }
        __syncthreads();
        As[kq+0][row]=a0.x; As[kq+1][row]=a0.y; As[kq+2][row]=a0.z; As[kq+3][row]=a0.w;
        As[kq+4][row]=a1.x; As[kq+5][row]=a1.y; As[kq+6][row]=a1.z; As[kq+7][row]=a1.w;
        Bs[kq+0][row]=w0.x; Bs[kq+1][row]=w0.y; Bs[kq+2][row]=w0.z; Bs[kq+3][row]=w0.w;
        Bs[kq+4][row]=w1.x; Bs[kq+5][row]=w1.y; Bs[kq+6][row]=w1.z; Bs[kq+7][row]=w1.w;
        __syncthreads();
#pragma unroll
        for (int kk = 0; kk < BK; ++kk) {
            float av[8], bv[8];
            *(float4*)&av[0] = *(const float4*)&As[kk][ty*8];
            *(float4*)&av[4] = *(const float4*)&As[kk][ty*8 + 4];
            *(float4*)&bv[0] = *(const float4*)&Bs[kk][tx*8];
            *(float4*)&bv[4] = *(const float4*)&Bs[kk][tx*8 + 4];
#pragma unroll
            for (int i = 0; i < 8; ++i)
#pragma unroll
                for (int j = 0; j < 8; ++j)
                    acc[i][j] = fmaf(av[i], bv[j], acc[i][j]);
        }
    }

    const float rs = (EPI == 1) ? rsp[0] : 0.f;
#pragma unroll
    for (int i = 0; i < 8; ++i) {
        const int mm = m0 + ty*8 + i;
        float* crow = C + (size_t)mm*N;
#pragma unroll
        for (int jq = 0; jq < 2; ++jq) {
            const int nn = n0 + tx*8 + jq*4;
            if (nn < N) {
                float4 o;
                o.x = acc[i][jq*4+0];
                o.y = acc[i][jq*4+1];
                o.z = acc[i][jq*4+2];
                o.w = acc[i][jq*4+3];
                if (EPI == 0) {
                    if (bias) {
                        float4 b4 = *(const float4*)(bias + nn);
                        o.x += b4.x; o.y += b4.y; o.z += b4.z; o.w += b4.w;
                    }
                } else if (EPI == 1) {
                    float4 cur = *(const float4*)(crow + nn);
                    o.x = fmaf(rs, o.x, cur.x);
                    o.y = fmaf(rs, o.y, cur.y);
                    o.z = fmaf(rs, o.z, cur.z);
                    o.w = fmaf(rs, o.w, cur.w);
                } else {
                    float4 b4 = *(const float4*)(bias + nn);
                    o.x = tanhf(o.x + b4.x);
                    o.y = tanhf(o.y + b4.y);
                    o.z = tanhf(o.z + b4.z);
                    o.w = tanhf(o.w + b4.w);
                }
                *(float4*)(crow + nn) = o;
            }
        }
    }
}

// ---------------------------------------------------------------------------
// LayerNorm over DM=256, 4 tokens per block (one per wave)
// ---------------------------------------------------------------------------
__global__ __launch_bounds__(256) void ln_k(
    const float* __restrict__ in, float* __restrict__ out,
    const float* __restrict__ g, const float* __restrict__ b)
{
    const int w = threadIdx.x >> 6;
    const int lane = threadIdx.x & 63;
    const int m = blockIdx.x*4 + w;
    const float4 v = *(const float4*)(in + (size_t)m*NDM + lane*4);
    float s = v.x+v.y+v.z+v.w;
    float q = v.x*v.x + v.y*v.y + v.z*v.z + v.w*v.w;
#pragma unroll
    for (int o = 32; o; o >>= 1) { s += __shfl_xor(s, o); q += __shfl_xor(q, o); }
    const float mu = s * (1.f/NDM);
    const float var = q * (1.f/NDM) - mu*mu;
    const float r = rsqrtf(var + 1e-5f);
    const float4 g4 = *(const float4*)(g + lane*4);
    const float4 b4 = *(const float4*)(b + lane*4);
    float4 o;
    o.x = (v.x-mu)*r*g4.x + b4.x;
    o.y = (v.y-mu)*r*g4.y + b4.y;
    o.z = (v.z-mu)*r*g4.z + b4.z;
    o.w = (v.w-mu)*r*g4.w + b4.w;
    *(float4*)(out + (size_t)m*NDM + lane*4) = o;
}

// ---------------------------------------------------------------------------
// depthwise causal conv (DC=4) + bias + silu; x = xz[..., :DI]
// ---------------------------------------------------------------------------
__global__ __launch_bounds__(256) void conv_k(
    const float* __restrict__ xz, const float* __restrict__ cw,
    const float* __restrict__ cb, float* __restrict__ xc)
{
    const int m = blockIdx.x >> 1;
    const int i = ((blockIdx.x & 1) << 8) + threadIdx.x;
    const int t = m & (NT-1);
    const float4 w4 = *(const float4*)(cw + i*4);   // taps k=0..3
    const float* base = xz + (size_t)m*(2*NDI) + i;
    float acc = cb[i] + base[0]*w4.w;                // x[t]   * cw[3]
    if (t >= 1) acc += base[-(2*NDI)]  * w4.z;       // x[t-1] * cw[2]
    if (t >= 2) acc += base[-2*(2*NDI)]* w4.y;       // x[t-2] * cw[1]
    if (t >= 3) acc += base[-3*(2*NDI)]* w4.x;       // x[t-3] * cw[0]
    xc[(size_t)m*NDI + i] = acc / (1.f + __expf(-acc));
}

// ---------------------------------------------------------------------------
// selective scan: block = 16 d-channels x 16 states, one batch element
// dt computed in staging (softplus(dbc[:, :16] @ dtw^T + dtb)); y += Dp*x
// ---------------------------------------------------------------------------
#define TCH 64
__global__ __launch_bounds__(256) void scan_k(
    const float* __restrict__ dbc,
    const float* __restrict__ xc,
    const float* __restrict__ dtw,
    const float* __restrict__ dtb,
    const float* __restrict__ Alog,
    const float* __restrict__ Dp,
    float* __restrict__ y)
{
    __shared__ float sR[TCH][16];
    __shared__ float sB[TCH][16];
    __shared__ float sC[TCH][16];
    __shared__ float sX[TCH][16];
    __shared__ float sDT[TCH][16];
    __shared__ float sY[TCH][16];
    const int tid = threadIdx.x;
    const int s = tid & 15;
    const int di = tid >> 4;
    const int b = blockIdx.x >> 5;
    const int d0 = (blockIdx.x & 31) << 4;
    const int d = d0 + di;
    const float Av = -__expf(Alog[d*NDS + s]);
    const float dpv = Dp[d];
    const float dtbd = dtb[d];
    float wrow[16];
#pragma unroll
    for (int r = 0; r < 16; ++r) wrow[r] = dtw[d*NR + r];
    float h = 0.f;
    const int jrow = tid >> 2;
    const int q4 = (tid & 3) << 2;
    const size_t mbase = (size_t)b * NT;
    for (int c0 = 0; c0 < NT; c0 += TCH) {
        __syncthreads();
        {
            const size_t m = mbase + c0 + jrow;
            const float* dp_ = dbc + m*48 + q4;
            *(float4*)&sR[jrow][q4] = *(const float4*)(dp_);
            *(float4*)&sB[jrow][q4] = *(const float4*)(dp_ + 16);
            *(float4*)&sC[jrow][q4] = *(const float4*)(dp_ + 32);
            *(float4*)&sX[jrow][q4] = *(const float4*)(xc + m*NDI + d0 + q4);
        }
        __syncthreads();
#pragma unroll
        for (int u2 = 0; u2 < 4; ++u2) {
            const int j = s + u2*16;
            float a = dtbd;
#pragma unroll
            for (int r = 0; r < 16; ++r) a = fmaf(sR[j][r], wrow[r], a);
            sDT[j][di] = (a > 20.f) ? a : log1pf(__expf(a));
        }
        __syncthreads();
        for (int j = 0; j < TCH; ++j) {
            const float dtv = sDT[j][di];
            const float xv = sX[j][di];
            const float Bv = sB[j][s];
            const float Cv = sC[j][s];
            const float pa = __expf(dtv * Av);
            h = fmaf(pa, h, dtv * Bv * xv);
            float cp = h * Cv;
            cp += __shfl_xor(cp, 1);
            cp += __shfl_xor(cp, 2);
            cp += __shfl_xor(cp, 4);
            cp += __shfl_xor(cp, 8);
            if (s == 0) sY[j][di] = fmaf(dpv, xv, cp);
        }
        __syncthreads();
        {
            const size_t m = mbase + c0 + jrow;
            *(float4*)(y + m*NDI + d0 + q4) = *(const float4*)&sY[jrow][q4];
        }
    }
}

// ---------------------------------------------------------------------------
// attention score reduce: s[m] = sum_h t1[m,h]*w2[h]
// ---------------------------------------------------------------------------
__global__ __launch_bounds__(64) void score_k(
    const float* __restrict__ t1, const float* __restrict__ w2,
    float* __restrict__ sout)
{
    const int m = blockIdx.x;
    const int lane = threadIdx.x;
    float v = t1[(size_t)m*NH + lane]*w2[lane]
            + t1[(size_t)m*NH + 64 + lane]*w2[64 + lane];
#pragma unroll
    for (int o = 32; o; o >>= 1) v += __shfl_xor(v, o);
    if (lane == 0) sout[m] = v;
}

// ---------------------------------------------------------------------------
// masked softmax over valid t + weighted pool of u -> ctx (one block per b)
// ---------------------------------------------------------------------------
__global__ __launch_bounds__(256) void pool_k(
    const float* __restrict__ sbuf, const float* __restrict__ u,
    const int* __restrict__ lengths, float* __restrict__ ctx)
{
    __shared__ float al[NT];
    __shared__ float red[256];
    const int b = blockIdx.x;
    const int tid = threadIdx.x;
    const int len = lengths[b];
    float mx = -3.4e38f;
    for (int t = tid; t < len; t += 256) mx = fmaxf(mx, sbuf[b*NT + t]);
    red[tid] = mx; __syncthreads();
    for (int o = 128; o; o >>= 1) { if (tid < o) red[tid] = fmaxf(red[tid], red[tid+o]); __syncthreads(); }
    mx = red[0];
    __syncthreads();
    float sm = 0.f;
    for (int t = tid; t < len; t += 256) {
        float e = __expf(sbuf[b*NT + t] - mx);
        al[t] = e; sm += e;
    }
    red[tid] = sm; __syncthreads();
    for (int o = 128; o; o >>= 1) { if (tid < o) red[tid] += red[tid+o]; __syncthreads(); }
    const float rZ = 1.f / red[0];
    float acc = 0.f;
    const float* up = u + (size_t)b*NT*NDM + tid;
    for (int t = 0; t < len; ++t) acc = fmaf(al[t], up[(size_t)t*NDM], acc);
    ctx[b*NDM + tid] = acc * rZ;
}

// ---------------------------------------------------------------------------
// head: out[b,c] = ctx[b,:] . head_w[c,:] + head_b[c]
// ---------------------------------------------------------------------------
__global__ __launch_bounds__(64) void head_k(
    const float* __restrict__ ctx, const float* __restrict__ hw,
    const float* __restrict__ hb, float* __restrict__ o)
{
    const int b = blockIdx.x;
    const int lane = threadIdx.x;
    const float4 c4 = *(const float4*)(ctx + b*NDM + lane*4);
#pragma unroll
    for (int c = 0; c < NNC; ++c) {
        const float4 w4 = *(const float4*)(hw + c*NDM + lane*4);
        float v = c4.x*w4.x + c4.y*w4.y + c4.z*w4.z + c4.w*w4.w;
#pragma unroll
        for (int off = 32; off; off >>= 1) v += __shfl_xor(v, off);
        if (lane == 0) o[b*NNC + c] = v + hb[c];
    }
}

// ---------------------------------------------------------------------------
extern "C" void kernel_launch(void* const* d_in, const int* in_sizes, int n_in,
                              void* d_out, int out_size, void* d_ws, size_t ws_size,
                              hipStream_t stream)
{
    (void)in_sizes; (void)n_in; (void)out_size; (void)ws_size;
    const float* x         = (const float*)d_in[0];
    const int*   lengths   = (const int*)  d_in[1];
    const float* tin_gamma = (const float*)d_in[2];
    const float* tin_beta  = (const float*)d_in[3];
    const float* proj_w    = (const float*)d_in[4];
    const float* proj_b    = (const float*)d_in[5];
    const float* ln_g      = (const float*)d_in[6];
    const float* ln_b      = (const float*)d_in[7];
    const float* in_proj_w = (const float*)d_in[8];
    const float* conv_w    = (const float*)d_in[9];
    const float* conv_b    = (const float*)d_in[10];
    const float* x_proj_w  = (const float*)d_in[11];
    const float* dt_proj_w = (const float*)d_in[12];
    const float* dt_proj_b = (const float*)d_in[13];
    const float* A_log     = (const float*)d_in[14];
    const float* D_param   = (const float*)d_in[15];
    const float* out_proj_w= (const float*)d_in[16];
    const float* out_ln_g  = (const float*)d_in[17];
    const float* out_ln_b  = (const float*)d_in[18];
    const float* res_scale = (const float*)d_in[19];
    const float* attn_w1   = (const float*)d_in[20];
    const float* attn_b1   = (const float*)d_in[21];
    const float* attn_w2   = (const float*)d_in[22];
    const float* head_w    = (const float*)d_in[23];
    const float* head_b    = (const float*)d_in[24];
    float* out = (float*)d_out;

    float* ws   = (float*)d_ws;
    float* mean = ws;                               // NB*ND
    float* rstd = mean + (size_t)NB*ND;             // NB*ND
    float* hbuf = rstd + (size_t)NB*ND;             // NM*NDM
    float* ubuf = hbuf + (size_t)NM*NDM;            // NM*NDM
    float* xz   = ubuf + (size_t)NM*NDM;            // NM*2*NDI
    float* xc   = xz   + (size_t)NM*2*NDI;          // NM*NDI
    float* ybuf = xc   + (size_t)NM*NDI;            // NM*NDI
    float* dbc  = ybuf + (size_t)NM*NDI;            // NM*48
    float* t1   = dbc  + (size_t)NM*48;             // NM*NH
    float* sbuf = t1   + (size_t)NM*NH;             // NM
    float* ctx  = sbuf + NM;                        // NB*NDM

    const dim3 blk(256);

    // instance-norm stats + projection (norm fused into A-load)
    tin_stats_k<<<dim3(NB*32), blk, 0, stream>>>(x, lengths, mean, rstd);
    gemm_k<1,0><<<dim3(NM/BM, NDM/BN), blk, 0, stream>>>(
        x, ND, nullptr, 0, proj_w, proj_b, hbuf, NM, NDM, ND,
        mean, rstd, tin_gamma, tin_beta, lengths, nullptr);

    for (int l = 0; l < NL; ++l) {
        ln_k<<<dim3(NM/4), blk, 0, stream>>>(hbuf, ubuf, ln_g + l*NDM, ln_b + l*NDM);
        gemm_k<0,0><<<dim3(NM/BM, (2*NDI)/BN), blk, 0, stream>>>(
            ubuf, NDM, nullptr, 0, in_proj_w + (size_t)l*2*NDI*NDM, nullptr,
            xz, NM, 2*NDI, NDM, nullptr, nullptr, nullptr, nullptr, nullptr, nullptr);
        conv_k<<<dim3(NM*2), blk, 0, stream>>>(
            xz, conv_w + (size_t)l*NDI*NDC, conv_b + (size_t)l*NDI, xc);
        gemm_k<0,0><<<dim3(NM/BM, 1), blk, 0, stream>>>(
            xc, NDI, nullptr, 0, x_proj_w + (size_t)l*48*NDI, nullptr,
            dbc, NM, 48, NDI, nullptr, nullptr, nullptr, nullptr, nullptr, nullptr);
        scan_k<<<dim3(NB*32), blk, 0, stream>>>(
            dbc, xc, dt_proj_w + (size_t)l*NDI*NR, dt_proj_b + (size_t)l*NDI,
            A_log + (size_t)l*NDI*NDS, D_param + (size_t)l*NDI, ybuf);
        gemm_k<2,1><<<dim3(NM/BM, NDM/BN), blk, 0, stream>>>(
            ybuf, NDI, xz + NDI, 2*NDI, out_proj_w + (size_t)l*NDM*NDI, nullptr,
            hbuf, NM, NDM, NDI, nullptr, nullptr, nullptr, nullptr, nullptr, res_scale);
    }

    ln_k<<<dim3(NM/4), blk, 0, stream>>>(hbuf, ubuf, out_ln_g, out_ln_b);
    gemm_k<0,2><<<dim3(NM/BM, 1), blk, 0, stream>>>(
        ubuf, NDM, nullptr, 0, attn_w1, attn_b1, t1, NM, NH, NDM,
        nullptr, nullptr, nullptr, nullptr, nullptr, nullptr);
    score_k<<<dim3(NM), dim3(64), 0, stream>>>(t1, attn_w2, sbuf);
    pool_k<<<dim3(NB), blk, 0, stream>>>(sbuf, ubuf, lengths, ctx);
    head_k<<<dim3(NB), dim3(64), 0, stream>>>(ctx, head_w, head_b, out);
}

// Round 2
// 1864.613 us; speedup vs baseline: 1.3429x; 1.3429x over previous
//
#include <hip/hip_runtime.h>

#define NB 32       // B
#define NT 512      // T
#define ND 2048     // D
#define NDM 256     // DM
#define NDI 512     // DI
#define NDS 16      // DS
#define NR 16       // R
#define NDC 4       // DC
#define NH 128      // H
#define NNC 8       // NC
#define NL 4        // L
#define NM (NB*NT)  // 16384 tokens

typedef __attribute__((ext_vector_type(8))) short short8;
typedef __attribute__((ext_vector_type(4))) float floatx4;

__device__ __forceinline__ unsigned short f2bf_rn(float f) {
    unsigned u = __builtin_bit_cast(unsigned, f);
    u += 0x7FFFu + ((u >> 16) & 1u);
    return (unsigned short)(u >> 16);
}

// ---------------------------------------------------------------------------
// masked time-instance-norm statistics: mean/rstd per (b,d)
// ---------------------------------------------------------------------------
__global__ __launch_bounds__(256) void tin_stats_k(
    const float* __restrict__ x, const int* __restrict__ lengths,
    float* __restrict__ mean, float* __restrict__ rstd)
{
    __shared__ float rs_[4][64];
    __shared__ float rq_[4][64];
    const int b = blockIdx.x >> 5;            // /32
    const int d0 = (blockIdx.x & 31) << 6;    // *64
    const int dl = threadIdx.x & 63;
    const int strip = threadIdx.x >> 6;       // 0..3
    const int len = lengths[b];
    const int d = d0 + dl;
    float s = 0.f, q = 0.f;
    for (int t = strip; t < len; t += 4) {
        float v = x[((size_t)(b*NT + t))*ND + d];
        s += v; q += v*v;
    }
    rs_[strip][dl] = s; rq_[strip][dl] = q;
    __syncthreads();
    if (threadIdx.x < 64) {
        float S = rs_[0][dl]+rs_[1][dl]+rs_[2][dl]+rs_[3][dl];
        float Q = rq_[0][dl]+rq_[1][dl]+rq_[2][dl]+rq_[3][dl];
        float inv = 1.f / (float)(len < 1 ? 1 : len);
        float mu = S * inv;
        float var = Q * inv - mu*mu;
        mean[b*ND + d] = mu;
        rstd[b*ND + d] = rsqrtf(var + 1e-5f);
    }
}

// ---------------------------------------------------------------------------
// Split-bf16 MFMA GEMM: C[M,N] (op)= A[M,K] @ W[N,K]^T
// Each fp32 value v ~ hi(bf16) + lo(bf16); product via 3 bf16 MFMAs
// (hi*hi + hi*lo + lo*hi), fp32 accumulate -> ~2^-17 relative error.
// Block tile 128x128, BK=32, 4 waves each computing 64x64 (4x4 MFMA tiles).
// LDS in fragment order: region[tile(8)][lane(64)][8 bf16] -> every
// ds_read_b128 / ds_write_b128 is lane-linear = conflict-free.
// AMODE 0: plain A; 1: A = instnorm(x) fused; 2: A = A * silu(A2)
// EPI 0: C = acc (+bias); EPI 1: C += rs*acc; EPI 2: C = tanh(acc+bias)
// ---------------------------------------------------------------------------
#define A_HI 0
#define A_LO 4096
#define B_HI 8192
#define B_LO 12288

template<int AMODE, int EPI>
__global__ __launch_bounds__(256) void mgemm_k(
    const float* __restrict__ A, int lda,
    const float* __restrict__ A2, int lda2,
    const float* __restrict__ W,
    const float* __restrict__ bias,
    float* __restrict__ C,
    int M, int N, int K,
    const float* __restrict__ mean, const float* __restrict__ rstd,
    const float* __restrict__ gamma, const float* __restrict__ beta,
    const int* __restrict__ lengths,
    const float* __restrict__ rsp)
{
    __shared__ __align__(16) short lds[16384];   // 32 KB: A_hi,A_lo,B_hi,B_lo
    const int tid = threadIdx.x;
    const int lane = tid & 63;
    const int w = tid >> 6;
    const int lm = lane & 15;     // staging row-in-tile
    const int lc = lane >> 4;     // staging k-chunk (0..3)
    const int wm = w >> 1;        // wave tile coords (2x2)
    const int wn = w & 1;
    const int m0 = blockIdx.x * 128;
    const int n0 = blockIdx.y * 128;

    int lenb = 0, bb = 0;
    if (AMODE == 1) { bb = m0 >> 9; lenb = lengths[bb]; }

    floatx4 acc[4][4];
#pragma unroll
    for (int i = 0; i < 4; ++i)
#pragma unroll
        for (int j = 0; j < 4; ++j) acc[i][j] = (floatx4){0.f,0.f,0.f,0.f};

    for (int k0 = 0; k0 < K; k0 += 32) {
        float va[2][8], vb[2][8];
        // ---- global loads: A rows (wave handles m-tiles 2w, 2w+1) ----
#pragma unroll
        for (int hh = 0; hh < 2; ++hh) {
            const int mt = w*2 + hh;
            const int gm = m0 + mt*16 + lm;
            const int kg = k0 + lc*8;
            const float* ap = A + (size_t)gm*lda + kg;
            float4 a0 = *(const float4*)ap;
            float4 a1 = *(const float4*)(ap + 4);
            if (AMODE == 1) {
                const int tcur = gm & (NT-1);
                if (tcur >= lenb) {
                    a0 = make_float4(0.f,0.f,0.f,0.f); a1 = a0;
                } else {
                    const int kb = bb*ND + kg;
                    float4 mn0 = *(const float4*)(mean + kb);
                    float4 mn1 = *(const float4*)(mean + kb + 4);
                    float4 rr0 = *(const float4*)(rstd + kb);
                    float4 rr1 = *(const float4*)(rstd + kb + 4);
                    float4 g0 = *(const float4*)(gamma + kg);
                    float4 g1 = *(const float4*)(gamma + kg + 4);
                    float4 e0 = *(const float4*)(beta + kg);
                    float4 e1 = *(const float4*)(beta + kg + 4);
                    a0.x = (a0.x - mn0.x)*rr0.x*g0.x + e0.x;
                    a0.y = (a0.y - mn0.y)*rr0.y*g0.y + e0.y;
                    a0.z = (a0.z - mn0.z)*rr0.z*g0.z + e0.z;
                    a0.w = (a0.w - mn0.w)*rr0.w*g0.w + e0.w;
                    a1.x = (a1.x - mn1.x)*rr1.x*g1.x + e1.x;
                    a1.y = (a1.y - mn1.y)*rr1.y*g1.y + e1.y;
                    a1.z = (a1.z - mn1.z)*rr1.z*g1.z + e1.z;
                    a1.w = (a1.w - mn1.w)*rr1.w*g1.w + e1.w;
                }
            } else if (AMODE == 2) {
                const float* zp = A2 + (size_t)gm*lda2 + kg;
                float4 z0 = *(const float4*)zp;
                float4 z1 = *(const float4*)(zp + 4);
                a0.x *= z0.x / (1.f + __expf(-z0.x));
                a0.y *= z0.y / (1.f + __expf(-z0.y));
                a0.z *= z0.z / (1.f + __expf(-z0.z));
                a0.w *= z0.w / (1.f + __expf(-z0.w));
                a1.x *= z1.x / (1.f + __expf(-z1.x));
                a1.y *= z1.y / (1.f + __expf(-z1.y));
                a1.z *= z1.z / (1.f + __expf(-z1.z));
                a1.w *= z1.w / (1.f + __expf(-z1.w));
            }
            va[hh][0]=a0.x; va[hh][1]=a0.y; va[hh][2]=a0.z; va[hh][3]=a0.w;
            va[hh][4]=a1.x; va[hh][5]=a1.y; va[hh][6]=a1.z; va[hh][7]=a1.w;
        }
        // ---- global loads: W rows (wave handles n-tiles 2w, 2w+1) ----
#pragma unroll
        for (int hh = 0; hh < 2; ++hh) {
            const int nt = w*2 + hh;
            const int gn = n0 + nt*16 + lm;
            float4 w0, w1;
            if (gn < N) {
                const float* wp = W + (size_t)gn*K + k0 + lc*8;
                w0 = *(const float4*)wp;
                w1 = *(const float4*)(wp + 4);
            } else {
                w0 = make_float4(0.f,0.f,0.f,0.f); w1 = w0;
            }
            vb[hh][0]=w0.x; vb[hh][1]=w0.y; vb[hh][2]=w0.z; vb[hh][3]=w0.w;
            vb[hh][4]=w1.x; vb[hh][5]=w1.y; vb[hh][6]=w1.z; vb[hh][7]=w1.w;
        }
        __syncthreads();   // previous iter's fragment reads complete
        // ---- convert to hi/lo bf16, write LDS in fragment order ----
#pragma unroll
        for (int hh = 0; hh < 2; ++hh) {
            short8 h8, l8;
#pragma unroll
            for (int q = 0; q < 8; ++q) {
                unsigned short hb = f2bf_rn(va[hh][q]);
                float hf = __builtin_bit_cast(float, (unsigned)hb << 16);
                h8[q] = (short)hb;
                l8[q] = (short)f2bf_rn(va[hh][q] - hf);
            }
            const int off = ((w*2 + hh)*64 + lane)*8;
            *(short8*)&lds[A_HI + off] = h8;
            *(short8*)&lds[A_LO + off] = l8;
        }
#pragma unroll
        for (int hh = 0; hh < 2; ++hh) {
            short8 h8, l8;
#pragma unroll
            for (int q = 0; q < 8; ++q) {
                unsigned short hb = f2bf_rn(vb[hh][q]);
                float hf = __builtin_bit_cast(float, (unsigned)hb << 16);
                h8[q] = (short)hb;
                l8[q] = (short)f2bf_rn(vb[hh][q] - hf);
            }
            const int off = ((w*2 + hh)*64 + lane)*8;
            *(short8*)&lds[B_HI + off] = h8;
            *(short8*)&lds[B_LO + off] = l8;
        }
        __syncthreads();
        // ---- fragments + MFMA ----
        short8 ah[4], al[4], bh[4], bl[4];
#pragma unroll
        for (int i = 0; i < 4; ++i) {
            const int off = ((wm*4 + i)*64 + lane)*8;
            ah[i] = *(const short8*)&lds[A_HI + off];
            al[i] = *(const short8*)&lds[A_LO + off];
        }
#pragma unroll
        for (int j = 0; j < 4; ++j) {
            const int off = ((wn*4 + j)*64 + lane)*8;
            bh[j] = *(const short8*)&lds[B_HI + off];
            bl[j] = *(const short8*)&lds[B_LO + off];
        }
#pragma unroll
        for (int i = 0; i < 4; ++i)
#pragma unroll
            for (int j = 0; j < 4; ++j) {
                acc[i][j] = __builtin_amdgcn_mfma_f32_16x16x32_bf16(ah[i], bh[j], acc[i][j], 0, 0, 0);
                acc[i][j] = __builtin_amdgcn_mfma_f32_16x16x32_bf16(ah[i], bl[j], acc[i][j], 0, 0, 0);
                acc[i][j] = __builtin_amdgcn_mfma_f32_16x16x32_bf16(al[i], bh[j], acc[i][j], 0, 0, 0);
            }
    }

    // ---- epilogue: C/D layout col = lane&15, row = (lane>>4)*4 + reg ----
    const float rs = (EPI == 1) ? rsp[0] : 0.f;
#pragma unroll
    for (int j = 0; j < 4; ++j) {
        const int n = n0 + wn*64 + j*16 + lm;
        if (n < N) {
            const float bv = (EPI != 1 && bias) ? bias[n] : 0.f;
#pragma unroll
            for (int i = 0; i < 4; ++i) {
#pragma unroll
                for (int r = 0; r < 4; ++r) {
                    const int m = m0 + wm*64 + i*16 + lc*4 + r;
                    float v = acc[i][j][r];
                    float* cp = C + (size_t)m*N + n;
                    if (EPI == 0)      *cp = v + bv;
                    else if (EPI == 1) *cp = fmaf(rs, v, *cp);
                    else               *cp = tanhf(v + bv);
                }
            }
        }
    }
}

// ---------------------------------------------------------------------------
// LayerNorm over DM=256, 4 tokens per block (one per wave)
// ---------------------------------------------------------------------------
__global__ __launch_bounds__(256) void ln_k(
    const float* __restrict__ in, float* __restrict__ out,
    const float* __restrict__ g, const float* __restrict__ b)
{
    const int w = threadIdx.x >> 6;
    const int lane = threadIdx.x & 63;
    const int m = blockIdx.x*4 + w;
    const float4 v = *(const float4*)(in + (size_t)m*NDM + lane*4);
    float s = v.x+v.y+v.z+v.w;
    float q = v.x*v.x + v.y*v.y + v.z*v.z + v.w*v.w;
#pragma unroll
    for (int o = 32; o; o >>= 1) { s += __shfl_xor(s, o); q += __shfl_xor(q, o); }
    const float mu = s * (1.f/NDM);
    const float var = q * (1.f/NDM) - mu*mu;
    const float r = rsqrtf(var + 1e-5f);
    const float4 g4 = *(const float4*)(g + lane*4);
    const float4 b4 = *(const float4*)(b + lane*4);
    float4 o;
    o.x = (v.x-mu)*r*g4.x + b4.x;
    o.y = (v.y-mu)*r*g4.y + b4.y;
    o.z = (v.z-mu)*r*g4.z + b4.z;
    o.w = (v.w-mu)*r*g4.w + b4.w;
    *(float4*)(out + (size_t)m*NDM + lane*4) = o;
}

// ---------------------------------------------------------------------------
// depthwise causal conv (DC=4) + bias + silu; x = xz[..., :DI]
// ---------------------------------------------------------------------------
__global__ __launch_bounds__(256) void conv_k(
    const float* __restrict__ xz, const float* __restrict__ cw,
    const float* __restrict__ cb, float* __restrict__ xc)
{
    const int m = blockIdx.x >> 1;
    const int i = ((blockIdx.x & 1) << 8) + threadIdx.x;
    const int t = m & (NT-1);
    const float4 w4 = *(const float4*)(cw + i*4);   // taps k=0..3
    const float* base = xz + (size_t)m*(2*NDI) + i;
    float acc = cb[i] + base[0]*w4.w;                // x[t]   * cw[3]
    if (t >= 1) acc += base[-(2*NDI)]  * w4.z;       // x[t-1] * cw[2]
    if (t >= 2) acc += base[-2*(2*NDI)]* w4.y;       // x[t-2] * cw[1]
    if (t >= 3) acc += base[-3*(2*NDI)]* w4.x;       // x[t-3] * cw[0]
    xc[(size_t)m*NDI + i] = acc / (1.f + __expf(-acc));
}

// ---------------------------------------------------------------------------
// selective scan: block = 16 d-channels x 16 states, one batch element
// ---------------------------------------------------------------------------
#define TCH 64
__global__ __launch_bounds__(256) void scan_k(
    const float* __restrict__ dbc,
    const float* __restrict__ xc,
    const float* __restrict__ dtw,
    const float* __restrict__ dtb,
    const float* __restrict__ Alog,
    const float* __restrict__ Dp,
    float* __restrict__ y)
{
    __shared__ float sR[TCH][16];
    __shared__ float sB[TCH][16];
    __shared__ float sC[TCH][16];
    __shared__ float sX[TCH][16];
    __shared__ float sDT[TCH][16];
    __shared__ float sY[TCH][16];
    const int tid = threadIdx.x;
    const int s = tid & 15;
    const int di = tid >> 4;
    const int b = blockIdx.x >> 5;
    const int d0 = (blockIdx.x & 31) << 4;
    const int d = d0 + di;
    const float Av = -__expf(Alog[d*NDS + s]);
    const float dpv = Dp[d];
    const float dtbd = dtb[d];
    float wrow[16];
#pragma unroll
    for (int r = 0; r < 16; ++r) wrow[r] = dtw[d*NR + r];
    float h = 0.f;
    const int jrow = tid >> 2;
    const int q4 = (tid & 3) << 2;
    const size_t mbase = (size_t)b * NT;
    for (int c0 = 0; c0 < NT; c0 += TCH) {
        __syncthreads();
        {
            const size_t m = mbase + c0 + jrow;
            const float* dp_ = dbc + m*48 + q4;
            *(float4*)&sR[jrow][q4] = *(const float4*)(dp_);
            *(float4*)&sB[jrow][q4] = *(const float4*)(dp_ + 16);
            *(float4*)&sC[jrow][q4] = *(const float4*)(dp_ + 32);
            *(float4*)&sX[jrow][q4] = *(const float4*)(xc + m*NDI + d0 + q4);
        }
        __syncthreads();
#pragma unroll
        for (int u2 = 0; u2 < 4; ++u2) {
            const int j = s + u2*16;
            float a = dtbd;
#pragma unroll
            for (int r = 0; r < 16; ++r) a = fmaf(sR[j][r], wrow[r], a);
            sDT[j][di] = (a > 20.f) ? a : log1pf(__expf(a));
        }
        __syncthreads();
        for (int j = 0; j < TCH; ++j) {
            const float dtv = sDT[j][di];
            const float xv = sX[j][di];
            const float Bv = sB[j][s];
            const float Cv = sC[j][s];
            const float pa = __expf(dtv * Av);
            h = fmaf(pa, h, dtv * Bv * xv);
            float cp = h * Cv;
            cp += __shfl_xor(cp, 1);
            cp += __shfl_xor(cp, 2);
            cp += __shfl_xor(cp, 4);
            cp += __shfl_xor(cp, 8);
            if (s == 0) sY[j][di] = fmaf(dpv, xv, cp);
        }
        __syncthreads();
        {
            const size_t m = mbase + c0 + jrow;
            *(float4*)(y + m*NDI + d0 + q4) = *(const float4*)&sY[jrow][q4];
        }
    }
}

// ---------------------------------------------------------------------------
// attention score reduce: s[m] = sum_h t1[m,h]*w2[h]
// ---------------------------------------------------------------------------
__global__ __launch_bounds__(64) void score_k(
    const float* __restrict__ t1, const float* __restrict__ w2,
    float* __restrict__ sout)
{
    const int m = blockIdx.x;
    const int lane = threadIdx.x;
    float v = t1[(size_t)m*NH + lane]*w2[lane]
            + t1[(size_t)m*NH + 64 + lane]*w2[64 + lane];
#pragma unroll
    for (int o = 32; o; o >>= 1) v += __shfl_xor(v, o);
    if (lane == 0) sout[m] = v;
}

// ---------------------------------------------------------------------------
// masked softmax over valid t + weighted pool of u -> ctx (one block per b)
// ---------------------------------------------------------------------------
__global__ __launch_bounds__(256) void pool_k(
    const float* __restrict__ sbuf, const float* __restrict__ u,
    const int* __restrict__ lengths, float* __restrict__ ctx)
{
    __shared__ float al[NT];
    __shared__ float red[256];
    const int b = blockIdx.x;
    const int tid = threadIdx.x;
    const int len = lengths[b];
    float mx = -3.4e38f;
    for (int t = tid; t < len; t += 256) mx = fmaxf(mx, sbuf[b*NT + t]);
    red[tid] = mx; __syncthreads();
    for (int o = 128; o; o >>= 1) { if (tid < o) red[tid] = fmaxf(red[tid], red[tid+o]); __syncthreads(); }
    mx = red[0];
    __syncthreads();
    float sm = 0.f;
    for (int t = tid; t < len; t += 256) {
        float e = __expf(sbuf[b*NT + t] - mx);
        al[t] = e; sm += e;
    }
    red[tid] = sm; __syncthreads();
    for (int o = 128; o; o >>= 1) { if (tid < o) red[tid] += red[tid+o]; __syncthreads(); }
    const float rZ = 1.f / red[0];
    float acc = 0.f;
    const float* up = u + (size_t)b*NT*NDM + tid;
    for (int t = 0; t < len; ++t) acc = fmaf(al[t], up[(size_t)t*NDM], acc);
    ctx[b*NDM + tid] = acc * rZ;
}

// ---------------------------------------------------------------------------
// head: out[b,c] = ctx[b,:] . head_w[c,:] + head_b[c]
// ---------------------------------------------------------------------------
__global__ __launch_bounds__(64) void head_k(
    const float* __restrict__ ctx, const float* __restrict__ hw,
    const float* __restrict__ hb, float* __restrict__ o)
{
    const int b = blockIdx.x;
    const int lane = threadIdx.x;
    const float4 c4 = *(const float4*)(ctx + b*NDM + lane*4);
#pragma unroll
    for (int c = 0; c < NNC; ++c) {
        const float4 w4 = *(const float4*)(hw + c*NDM + lane*4);
        float v = c4.x*w4.x + c4.y*w4.y + c4.z*w4.z + c4.w*w4.w;
#pragma unroll
        for (int off = 32; off; off >>= 1) v += __shfl_xor(v, off);
        if (lane == 0) o[b*NNC + c] = v + hb[c];
    }
}

// ---------------------------------------------------------------------------
extern "C" void kernel_launch(void* const* d_in, const int* in_sizes, int n_in,
                              void* d_out, int out_size, void* d_ws, size_t ws_size,
                              hipStream_t stream)
{
    (void)in_sizes; (void)n_in; (void)out_size; (void)ws_size;
    const float* x         = (const float*)d_in[0];
    const int*   lengths   = (const int*)  d_in[1];
    const float* tin_gamma = (const float*)d_in[2];
    const float* tin_beta  = (const float*)d_in[3];
    const float* proj_w    = (const float*)d_in[4];
    const float* proj_b    = (const float*)d_in[5];
    const float* ln_g      = (const float*)d_in[6];
    const float* ln_b      = (const float*)d_in[7];
    const float* in_proj_w = (const float*)d_in[8];
    const float* conv_w    = (const float*)d_in[9];
    const float* conv_b    = (const float*)d_in[10];
    const float* x_proj_w  = (const float*)d_in[11];
    const float* dt_proj_w = (const float*)d_in[12];
    const float* dt_proj_b = (const float*)d_in[13];
    const float* A_log     = (const float*)d_in[14];
    const float* D_param   = (const float*)d_in[15];
    const float* out_proj_w= (const float*)d_in[16];
    const float* out_ln_g  = (const float*)d_in[17];
    const float* out_ln_b  = (const float*)d_in[18];
    const float* res_scale = (const float*)d_in[19];
    const float* attn_w1   = (const float*)d_in[20];
    const float* attn_b1   = (const float*)d_in[21];
    const float* attn_w2   = (const float*)d_in[22];
    const float* head_w    = (const float*)d_in[23];
    const float* head_b    = (const float*)d_in[24];
    float* out = (float*)d_out;

    float* ws   = (float*)d_ws;
    float* mean = ws;                               // NB*ND
    float* rstd = mean + (size_t)NB*ND;             // NB*ND
    float* hbuf = rstd + (size_t)NB*ND;             // NM*NDM
    float* ubuf = hbuf + (size_t)NM*NDM;            // NM*NDM
    float* xz   = ubuf + (size_t)NM*NDM;            // NM*2*NDI
    float* xc   = xz   + (size_t)NM*2*NDI;          // NM*NDI
    float* ybuf = xc   + (size_t)NM*NDI;            // NM*NDI
    float* dbc  = ybuf + (size_t)NM*NDI;            // NM*48
    float* t1   = dbc  + (size_t)NM*48;             // NM*NH
    float* sbuf = t1   + (size_t)NM*NH;             // NM
    float* ctx  = sbuf + NM;                        // NB*NDM

    const dim3 blk(256);

    // instance-norm stats + projection (norm fused into A-load)
    tin_stats_k<<<dim3(NB*32), blk, 0, stream>>>(x, lengths, mean, rstd);
    mgemm_k<1,0><<<dim3(NM/128, NDM/128), blk, 0, stream>>>(
        x, ND, nullptr, 0, proj_w, proj_b, hbuf, NM, NDM, ND,
        mean, rstd, tin_gamma, tin_beta, lengths, nullptr);

    for (int l = 0; l < NL; ++l) {
        ln_k<<<dim3(NM/4), blk, 0, stream>>>(hbuf, ubuf, ln_g + l*NDM, ln_b + l*NDM);
        mgemm_k<0,0><<<dim3(NM/128, (2*NDI)/128), blk, 0, stream>>>(
            ubuf, NDM, nullptr, 0, in_proj_w + (size_t)l*2*NDI*NDM, nullptr,
            xz, NM, 2*NDI, NDM, nullptr, nullptr, nullptr, nullptr, nullptr, nullptr);
        conv_k<<<dim3(NM*2), blk, 0, stream>>>(
            xz, conv_w + (size_t)l*NDI*NDC, conv_b + (size_t)l*NDI, xc);
        mgemm_k<0,0><<<dim3(NM/128, 1), blk, 0, stream>>>(
            xc, NDI, nullptr, 0, x_proj_w + (size_t)l*48*NDI, nullptr,
            dbc, NM, 48, NDI, nullptr, nullptr, nullptr, nullptr, nullptr, nullptr);
        scan_k<<<dim3(NB*32), blk, 0, stream>>>(
            dbc, xc, dt_proj_w + (size_t)l*NDI*NR, dt_proj_b + (size_t)l*NDI,
            A_log + (size_t)l*NDI*NDS, D_param + (size_t)l*NDI, ybuf);
        mgemm_k<2,1><<<dim3(NM/128, NDM/128), blk, 0, stream>>>(
            ybuf, NDI, xz + NDI, 2*NDI, out_proj_w + (size_t)l*NDM*NDI, nullptr,
            hbuf, NM, NDM, NDI, nullptr, nullptr, nullptr, nullptr, nullptr, res_scale);
    }

    ln_k<<<dim3(NM/4), blk, 0, stream>>>(hbuf, ubuf, out_ln_g, out_ln_b);
    mgemm_k<0,2><<<dim3(NM/128, 1), blk, 0, stream>>>(
        ubuf, NDM, nullptr, 0, attn_w1, attn_b1, t1, NM, NH, NDM,
        nullptr, nullptr, nullptr, nullptr, nullptr, nullptr);
    score_k<<<dim3(NM), dim3(64), 0, stream>>>(t1, attn_w2, sbuf);
    pool_k<<<dim3(NB), blk, 0, stream>>>(sbuf, ubuf, lengths, ctx);
    head_k<<<dim3(NB), dim3(64), 0, stream>>>(ctx, head_w, head_b, out);
}

// Round 3
// 1644.358 us; speedup vs baseline: 1.5228x; 1.1339x over previous
//
#include <hip/hip_runtime.h>

#define NB 32       // B
#define NT 512      // T
#define ND 2048     // D
#define NDM 256     // DM
#define NDI 512     // DI
#define NDS 16      // DS
#define NR 16       // R
#define NH 128      // H
#define NNC 8       // NC
#define NL 4        // L
#define NM (NB*NT)  // 16384 tokens

typedef __attribute__((ext_vector_type(8))) short short8;
typedef __attribute__((ext_vector_type(4))) float floatx4;

__device__ __forceinline__ unsigned short f2bf_rn(float f) {
    unsigned u = __builtin_bit_cast(unsigned, f);
    u += 0x7FFFu + ((u >> 16) & 1u);
    return (unsigned short)(u >> 16);
}
__device__ __forceinline__ void cvt8(const float* v, short8& h8, short8& l8) {
#pragma unroll
    for (int q = 0; q < 8; ++q) {
        unsigned short hb = f2bf_rn(v[q]);
        float hf = __builtin_bit_cast(float, (unsigned)hb << 16);
        h8[q] = (short)hb;
        l8[q] = (short)f2bf_rn(v[q] - hf);
    }
}

// ---------------------------------------------------------------------------
// masked time-instance-norm statistics: mean/rstd per (b,d)
// ---------------------------------------------------------------------------
__global__ __launch_bounds__(256) void tin_stats_k(
    const float* __restrict__ x, const int* __restrict__ lengths,
    float* __restrict__ mean, float* __restrict__ rstd)
{
    __shared__ float rs_[4][64];
    __shared__ float rq_[4][64];
    const int b = blockIdx.x >> 5;
    const int d0 = (blockIdx.x & 31) << 6;
    const int dl = threadIdx.x & 63;
    const int strip = threadIdx.x >> 6;
    const int len = lengths[b];
    const int d = d0 + dl;
    float s = 0.f, q = 0.f;
    for (int t = strip; t < len; t += 4) {
        float v = x[((size_t)(b*NT + t))*ND + d];
        s += v; q += v*v;
    }
    rs_[strip][dl] = s; rq_[strip][dl] = q;
    __syncthreads();
    if (threadIdx.x < 64) {
        float S = rs_[0][dl]+rs_[1][dl]+rs_[2][dl]+rs_[3][dl];
        float Q = rq_[0][dl]+rq_[1][dl]+rq_[2][dl]+rq_[3][dl];
        float inv = 1.f / (float)(len < 1 ? 1 : len);
        float mu = S * inv;
        float var = Q * inv - mu*mu;
        mean[b*ND + d] = mu;
        rstd[b*ND + d] = rsqrtf(var + 1e-5f);
    }
}

// ---------------------------------------------------------------------------
// instnorm(x) -> blocked-fragment bf16 hi/lo (A of proj GEMM)
// block = 16-token m-tile x 256-dim k-chunk; grid (NM/16, ND/256)
// ---------------------------------------------------------------------------
#define SLN 264   // padded LDS stride (floats)
__global__ __launch_bounds__(256) void tin_norm_k(
    const float* __restrict__ x, const int* __restrict__ lengths,
    const float* __restrict__ mean, const float* __restrict__ rstd,
    const float* __restrict__ g, const float* __restrict__ be,
    short* __restrict__ Oh, short* __restrict__ Ol)
{
    __shared__ float sT[16][SLN];
    const int tid = threadIdx.x;
    const int row = tid >> 4, c = tid & 15;
    const int m = blockIdx.x*16 + row;
    const int b = m >> 9, t = m & (NT-1);
    const int len = lengths[b];
    const int kg0 = blockIdx.y*256 + c*16;
    if (t >= len) {
#pragma unroll
        for (int i = 0; i < 16; ++i) sT[row][c*16 + i] = 0.f;
    } else {
#pragma unroll
        for (int qq = 0; qq < 4; ++qq) {
            const int kg = kg0 + qq*4;
            float4 v = *(const float4*)(x + (size_t)m*ND + kg);
            float4 mn = *(const float4*)(mean + b*ND + kg);
            float4 rr = *(const float4*)(rstd + b*ND + kg);
            float4 gg = *(const float4*)(g + kg);
            float4 bb = *(const float4*)(be + kg);
            sT[row][c*16+qq*4+0] = (v.x-mn.x)*rr.x*gg.x + bb.x;
            sT[row][c*16+qq*4+1] = (v.y-mn.y)*rr.y*gg.y + bb.y;
            sT[row][c*16+qq*4+2] = (v.z-mn.z)*rr.z*gg.z + bb.z;
            sT[row][c*16+qq*4+3] = (v.w-mn.w)*rr.w*gg.w + bb.w;
        }
    }
    __syncthreads();
#pragma unroll
    for (int q = 0; q < 2; ++q) {
        const int slot = tid + 256*q;
        const int tile = slot >> 6, ln2 = slot & 63;
        const int mr = ln2 & 15, kc = ln2 >> 4;
        float v[8];
        *(float4*)&v[0] = *(const float4*)&sT[mr][tile*32 + kc*8];
        *(float4*)&v[4] = *(const float4*)&sT[mr][tile*32 + kc*8 + 4];
        short8 h8, l8; cvt8(v, h8, l8);
        const size_t off = ((size_t)blockIdx.x*64 + blockIdx.y*8 + tile)*512 + ln2*8;
        *(short8*)(Oh + off) = h8;
        *(short8*)(Ol + off) = l8;
    }
}

// ---------------------------------------------------------------------------
// weight converter: W[N][K] fp32 row-major -> blocked hi/lo bf16
// nmod/nvalid: rows r with (r % nmod) >= nvalid are zero (x_proj padding)
// ---------------------------------------------------------------------------
__global__ __launch_bounds__(256) void wconv_k(
    const float* __restrict__ W, short* __restrict__ Oh, short* __restrict__ Ol,
    int K, int nmod, int nvalid)
{
    __shared__ float sT[16][SLN];
    const int tid = threadIdx.x;
    const int row = tid >> 4, c = tid & 15;
    const int n = blockIdx.x*16 + row;
    const int rr = n % nmod;
    const int kg0 = blockIdx.y*256 + c*16;
    if (rr >= nvalid) {
#pragma unroll
        for (int i = 0; i < 16; ++i) sT[row][c*16 + i] = 0.f;
    } else {
        const int src = (n/nmod)*nvalid + rr;
#pragma unroll
        for (int qq = 0; qq < 4; ++qq) {
            float4 v = *(const float4*)(W + (size_t)src*K + kg0 + qq*4);
            *(float4*)&sT[row][c*16+qq*4] = v;
        }
    }
    __syncthreads();
#pragma unroll
    for (int q = 0; q < 2; ++q) {
        const int slot = tid + 256*q;
        const int tile = slot >> 6, ln2 = slot & 63;
        const int mr = ln2 & 15, kc = ln2 >> 4;
        float v[8];
        *(float4*)&v[0] = *(const float4*)&sT[mr][tile*32 + kc*8];
        *(float4*)&v[4] = *(const float4*)&sT[mr][tile*32 + kc*8 + 4];
        short8 h8, l8; cvt8(v, h8, l8);
        const size_t off = ((size_t)blockIdx.x*(K>>5) + blockIdx.y*8 + tile)*512 + ln2*8;
        *(short8*)(Oh + off) = h8;
        *(short8*)(Ol + off) = l8;
    }
}

// ---------------------------------------------------------------------------
// Split-bf16 MFMA GEMM on pre-blocked operands.
// C[M,N] (op)= A[M,K] @ W[N,K]^T ; 3 MFMAs per product (hh+hl+lh).
// Block tile (MSUB*16) x (NSUB*16), BK=32, 4 waves in 2x2.
// EPI 0: C=acc(+bias); 1: C += rs*acc; 2: C=tanh(acc+bias)
// ---------------------------------------------------------------------------
template<int MSUB, int NSUB, int EPI>
__global__ __launch_bounds__(256) void mgemm_k(
    const short* __restrict__ Ah, const short* __restrict__ Al,
    const short* __restrict__ Bh, const short* __restrict__ Bl,
    const float* __restrict__ bias, float* __restrict__ C,
    int ldc, int Nvalid, int K, const float* __restrict__ rsp)
{
    __shared__ __align__(16) short lds[(MSUB+NSUB)*1024];
    short* As_h = lds;
    short* As_l = lds + MSUB*512;
    short* Bs_h = lds + MSUB*1024;
    short* Bs_l = lds + MSUB*1024 + NSUB*512;
    const int tid = threadIdx.x, lane = tid & 63, w = tid >> 6;
    const int m0t = blockIdx.x * MSUB;
    const int n0t = blockIdx.y * NSUB;
    const int Ktiles = K >> 5;
    constexpr int MI = MSUB/2, NI = NSUB/2;
    constexpr int ASG = MSUB/4, BSG = NSUB/4;
    const int wm = w >> 1, wn = w & 1;

    floatx4 acc[MI][NI] = {};
    short8 rah[ASG], ral[ASG], rbh[BSG], rbl[BSG];

#pragma unroll
    for (int u = 0; u < ASG; ++u) {
        const size_t off = ((size_t)(m0t + w*ASG + u)*Ktiles)*512 + lane*8;
        rah[u] = *(const short8*)(Ah + off); ral[u] = *(const short8*)(Al + off);
    }
#pragma unroll
    for (int u = 0; u < BSG; ++u) {
        const size_t off = ((size_t)(n0t + w*BSG + u)*Ktiles)*512 + lane*8;
        rbh[u] = *(const short8*)(Bh + off); rbl[u] = *(const short8*)(Bl + off);
    }

    for (int kb = 0; kb < Ktiles; ++kb) {
        __syncthreads();
#pragma unroll
        for (int u = 0; u < ASG; ++u) {
            const int sub = w*ASG + u;
            *(short8*)&As_h[sub*512 + lane*8] = rah[u];
            *(short8*)&As_l[sub*512 + lane*8] = ral[u];
        }
#pragma unroll
        for (int u = 0; u < BSG; ++u) {
            const int sub = w*BSG + u;
            *(short8*)&Bs_h[sub*512 + lane*8] = rbh[u];
            *(short8*)&Bs_l[sub*512 + lane*8] = rbl[u];
        }
        __syncthreads();
        if (kb + 1 < Ktiles) {
#pragma unroll
            for (int u = 0; u < ASG; ++u) {
                const size_t off = ((size_t)(m0t + w*ASG + u)*Ktiles + kb + 1)*512 + lane*8;
                rah[u] = *(const short8*)(Ah + off); ral[u] = *(const short8*)(Al + off);
            }
#pragma unroll
            for (int u = 0; u < BSG; ++u) {
                const size_t off = ((size_t)(n0t + w*BSG + u)*Ktiles + kb + 1)*512 + lane*8;
                rbh[u] = *(const short8*)(Bh + off); rbl[u] = *(const short8*)(Bl + off);
            }
        }
        short8 fah[MI], fal[MI], fbh[NI], fbl[NI];
#pragma unroll
        for (int i = 0; i < MI; ++i) {
            const int sub = wm*MI + i;
            fah[i] = *(const short8*)&As_h[sub*512 + lane*8];
            fal[i] = *(const short8*)&As_l[sub*512 + lane*8];
        }
#pragma unroll
        for (int j = 0; j < NI; ++j) {
            const int sub = wn*NI + j;
            fbh[j] = *(const short8*)&Bs_h[sub*512 + lane*8];
            fbl[j] = *(const short8*)&Bs_l[sub*512 + lane*8];
        }
#pragma unroll
        for (int i = 0; i < MI; ++i)
#pragma unroll
            for (int j = 0; j < NI; ++j) {
                acc[i][j] = __builtin_amdgcn_mfma_f32_16x16x32_bf16(fah[i], fbh[j], acc[i][j], 0, 0, 0);
                acc[i][j] = __builtin_amdgcn_mfma_f32_16x16x32_bf16(fah[i], fbl[j], acc[i][j], 0, 0, 0);
                acc[i][j] = __builtin_amdgcn_mfma_f32_16x16x32_bf16(fal[i], fbh[j], acc[i][j], 0, 0, 0);
            }
    }

    const float rs = (EPI == 1) ? rsp[0] : 0.f;
    const int lc = lane >> 4, col = lane & 15;
#pragma unroll
    for (int j = 0; j < NI; ++j) {
        const int n = (n0t + wn*NI + j)*16 + col;
        if (n < Nvalid) {
            const float bv = (EPI != 1 && bias) ? bias[n] : 0.f;
#pragma unroll
            for (int i = 0; i < MI; ++i) {
                const int mb = (m0t + wm*MI + i)*16 + lc*4;
#pragma unroll
                for (int r = 0; r < 4; ++r) {
                    float v = acc[i][j][r];
                    float* cp = C + (size_t)(mb + r)*ldc + n;
                    if (EPI == 0)      *cp = v + bv;
                    else if (EPI == 1) *cp = fmaf(rs, v, *cp);
                    else               *cp = tanhf(v + bv);
                }
            }
        }
    }
}

// ---------------------------------------------------------------------------
// LayerNorm over DM=256 -> blocked bf16 hi/lo (+ optional fp32 row-major)
// block = 16-token m-tile; grid NM/16
// ---------------------------------------------------------------------------
template<int WF32>
__global__ __launch_bounds__(256) void ln_blk_k(
    const float* __restrict__ in, const float* __restrict__ g,
    const float* __restrict__ b,
    short* __restrict__ Oh, short* __restrict__ Ol, float* __restrict__ o32)
{
    __shared__ float sT[16][SLN];
    const int tid = threadIdx.x;
    const int row = tid >> 4, c = tid & 15;
    const int m = blockIdx.x*16 + row;
    float v[16];
#pragma unroll
    for (int qq = 0; qq < 4; ++qq)
        *(float4*)&v[qq*4] = *(const float4*)(in + (size_t)m*NDM + c*16 + qq*4);
    float s = 0.f, q = 0.f;
#pragma unroll
    for (int i = 0; i < 16; ++i) { s += v[i]; q += v[i]*v[i]; }
#pragma unroll
    for (int o = 8; o; o >>= 1) { s += __shfl_xor(s, o); q += __shfl_xor(q, o); }
    const float mu = s * (1.f/NDM);
    const float r = rsqrtf(q*(1.f/NDM) - mu*mu + 1e-5f);
#pragma unroll
    for (int i = 0; i < 16; ++i) {
        const int kg = c*16 + i;
        v[i] = (v[i]-mu)*r*g[kg] + b[kg];
        sT[row][kg] = v[i];
    }
    if (WF32) {
#pragma unroll
        for (int qq = 0; qq < 4; ++qq)
            *(float4*)(o32 + (size_t)m*NDM + c*16 + qq*4) = *(const float4*)&v[qq*4];
    }
    __syncthreads();
#pragma unroll
    for (int qv = 0; qv < 2; ++qv) {
        const int slot = tid + 256*qv;
        const int tile = slot >> 6, ln2 = slot & 63;
        const int mr = ln2 & 15, kc = ln2 >> 4;
        float vv[8];
        *(float4*)&vv[0] = *(const float4*)&sT[mr][tile*32 + kc*8];
        *(float4*)&vv[4] = *(const float4*)&sT[mr][tile*32 + kc*8 + 4];
        short8 h8, l8; cvt8(vv, h8, l8);
        const size_t off = ((size_t)blockIdx.x*8 + tile)*512 + ln2*8;
        *(short8*)(Oh + off) = h8;
        *(short8*)(Ol + off) = l8;
    }
}

// ---------------------------------------------------------------------------
// depthwise causal conv(4) + silu -> xc fp32 row-major AND blocked hi/lo
// block = 16-token m-tile (512 ch); grid NM/16
// ---------------------------------------------------------------------------
#define SCV 520
__global__ __launch_bounds__(256) void conv_blk_k(
    const float* __restrict__ xz, const float* __restrict__ cw,
    const float* __restrict__ cb, float* __restrict__ xc32,
    short* __restrict__ Oh, short* __restrict__ Ol)
{
    __shared__ float sT[16][SCV];
    const int tid = threadIdx.x;
    const int row = tid >> 4, cg = tid & 15;
    const int m = blockIdx.x*16 + row;
    const int t = m & (NT-1);
#pragma unroll
    for (int grp = 0; grp < 4; ++grp) {
        const int ch = cg*32 + grp*8;
        float a[8];
        *(float4*)&a[0] = *(const float4*)(cb + ch);
        *(float4*)&a[4] = *(const float4*)(cb + ch + 4);
        float4 wv[8];
#pragma unroll
        for (int i = 0; i < 8; ++i) wv[i] = *(const float4*)(cw + (ch+i)*4);
#pragma unroll
        for (int kk = 0; kk < 4; ++kk) {
            if (t - 3 + kk >= 0) {
                const float* xp = xz + (size_t)(m-3+kk)*(2*NDI) + ch;
                float xv[8];
                *(float4*)&xv[0] = *(const float4*)xp;
                *(float4*)&xv[4] = *(const float4*)(xp + 4);
                const float tap[8] = {
                    kk==0?wv[0].x:kk==1?wv[0].y:kk==2?wv[0].z:wv[0].w,
                    kk==0?wv[1].x:kk==1?wv[1].y:kk==2?wv[1].z:wv[1].w,
                    kk==0?wv[2].x:kk==1?wv[2].y:kk==2?wv[2].z:wv[2].w,
                    kk==0?wv[3].x:kk==1?wv[3].y:kk==2?wv[3].z:wv[3].w,
                    kk==0?wv[4].x:kk==1?wv[4].y:kk==2?wv[4].z:wv[4].w,
                    kk==0?wv[5].x:kk==1?wv[5].y:kk==2?wv[5].z:wv[5].w,
                    kk==0?wv[6].x:kk==1?wv[6].y:kk==2?wv[6].z:wv[6].w,
                    kk==0?wv[7].x:kk==1?wv[7].y:kk==2?wv[7].z:wv[7].w};
#pragma unroll
                for (int i = 0; i < 8; ++i) a[i] = fmaf(xv[i], tap[i], a[i]);
            }
        }
#pragma unroll
        for (int i = 0; i < 8; ++i) a[i] = a[i] / (1.f + __expf(-a[i]));
        *(float4*)&sT[row][ch] = *(const float4*)&a[0];
        *(float4*)&sT[row][ch+4] = *(const float4*)&a[4];
        *(float4*)(xc32 + (size_t)m*NDI + ch) = *(const float4*)&a[0];
        *(float4*)(xc32 + (size_t)m*NDI + ch + 4) = *(const float4*)&a[4];
    }
    __syncthreads();
#pragma unroll
    for (int q = 0; q < 4; ++q) {
        const int slot = tid + 256*q;
        const int tile = slot >> 6, ln2 = slot & 63;
        const int mr = ln2 & 15, kc = ln2 >> 4;
        float vv[8];
        *(float4*)&vv[0] = *(const float4*)&sT[mr][tile*32 + kc*8];
        *(float4*)&vv[4] = *(const float4*)&sT[mr][tile*32 + kc*8 + 4];
        short8 h8, l8; cvt8(vv, h8, l8);
        const size_t off = ((size_t)blockIdx.x*16 + tile)*512 + ln2*8;
        *(short8*)(Oh + off) = h8;
        *(short8*)(Ol + off) = l8;
    }
}

// ---------------------------------------------------------------------------
// dt[m][d] = softplus(dbc[m][0:16] . dtw[d] + dtb[d]); grid NM blocks
// ---------------------------------------------------------------------------
__global__ __launch_bounds__(256) void dt_k(
    const float* __restrict__ dbc, const float* __restrict__ dtw,
    const float* __restrict__ dtb, float* __restrict__ dt)
{
    const int m = blockIdx.x;
    const float* rsrc = dbc + (size_t)m*48;
    float rv[16];
#pragma unroll
    for (int i = 0; i < 16; ++i) rv[i] = rsrc[i];
#pragma unroll
    for (int hh = 0; hh < 2; ++hh) {
        const int d = hh*256 + threadIdx.x;
        const float* wr = dtw + d*16;
        float a = dtb[d];
#pragma unroll
        for (int i = 0; i < 16; ++i) a = fmaf(rv[i], wr[i], a);
        dt[(size_t)m*NDI + d] = (a > 20.f) ? a : log1pf(__expf(a));
    }
}

// ---------------------------------------------------------------------------
// selective scan, register-state: 4 states/thread, 4 lanes per channel.
// block = 256 thr = 64 channels x 4 state-groups, one b; grid NB*8.
// epilogue per 64-t chunk: y*silu(z) -> blocked bf16 hi/lo (A of out_proj)
// ---------------------------------------------------------------------------
__global__ __launch_bounds__(256) void scan_k(
    const float* __restrict__ dbc, const float* __restrict__ dtp,
    const float* __restrict__ xcp, const float* __restrict__ xz,
    const float* __restrict__ Alog, const float* __restrict__ Dp,
    short* __restrict__ Yh, short* __restrict__ Yl)
{
    __shared__ float sBC[64][32];
    __shared__ float sY[64][68];
    const int tid = threadIdx.x;
    const int w = tid >> 6, lane = tid & 63;
    const int dl = lane >> 2, sg = lane & 3;
    const int b = blockIdx.x >> 3;
    const int d0 = (blockIdx.x & 7) << 6;
    const int dloc = w*16 + dl;
    const int d = d0 + dloc;
    float ar[4];
    {
        float4 al4 = *(const float4*)(Alog + d*NDS + sg*4);
        ar[0] = -__expf(al4.x); ar[1] = -__expf(al4.y);
        ar[2] = -__expf(al4.z); ar[3] = -__expf(al4.w);
    }
    const float Dpv = Dp[d];
    float hr[4] = {0.f, 0.f, 0.f, 0.f};
    const int mbase = b*NT;
    const int srow = tid >> 2, sq = (tid & 3) << 3;

    for (int c0 = 0; c0 < NT; c0 += 64) {
        // stage B/C rows for the chunk
        {
            const float* dp_ = dbc + (size_t)(mbase + c0 + srow)*48 + 16 + sq;
            *(float4*)&sBC[srow][sq]   = *(const float4*)dp_;
            *(float4*)&sBC[srow][sq+4] = *(const float4*)(dp_ + 4);
        }
        __syncthreads();
        float pdt[2][4], px[2][4];
#pragma unroll
        for (int u = 0; u < 4; ++u) {
            const size_t mm = (size_t)(mbase + c0 + u);
            pdt[0][u] = dtp[mm*NDI + d];
            px[0][u]  = xcp[mm*NDI + d];
        }
#pragma unroll
        for (int tg = 0; tg < 16; ++tg) {
            const int cur = tg & 1, nxt = cur ^ 1;
            if (tg < 15) {
#pragma unroll
                for (int u = 0; u < 4; ++u) {
                    const size_t mm = (size_t)(mbase + c0 + (tg+1)*4 + u);
                    pdt[nxt][u] = dtp[mm*NDI + d];
                    px[nxt][u]  = xcp[mm*NDI + d];
                }
            }
#pragma unroll
            for (int u = 0; u < 4; ++u) {
                const int tloc = tg*4 + u;
                const float dtv = pdt[cur][u], xv = px[cur][u];
                const float4 Bv = *(const float4*)&sBC[tloc][sg*4];
                const float4 Cv = *(const float4*)&sBC[tloc][16 + sg*4];
                const float dbx = dtv * xv;
                float cp;
                {
                    float pa = __expf(dtv*ar[0]); hr[0] = fmaf(pa, hr[0], dbx*Bv.x); cp = hr[0]*Cv.x;
                    pa = __expf(dtv*ar[1]); hr[1] = fmaf(pa, hr[1], dbx*Bv.y); cp = fmaf(hr[1], Cv.y, cp);
                    pa = __expf(dtv*ar[2]); hr[2] = fmaf(pa, hr[2], dbx*Bv.z); cp = fmaf(hr[2], Cv.z, cp);
                    pa = __expf(dtv*ar[3]); hr[3] = fmaf(pa, hr[3], dbx*Bv.w); cp = fmaf(hr[3], Cv.w, cp);
                }
                cp += __shfl_xor(cp, 1);
                cp += __shfl_xor(cp, 2);
                if (sg == 0) sY[tloc][dloc] = fmaf(Dpv, xv, cp);
            }
        }
        __syncthreads();
        // pack chunk: y * silu(z) -> blocked bf16
#pragma unroll
        for (int q = 0; q < 2; ++q) {
            const int slot = tid + 256*q;
            const int tile = slot >> 6, ln2 = slot & 63;
            const int tm = tile >> 1, tk = tile & 1;
            const int mr = ln2 & 15, kc = ln2 >> 4;
            const int m = mbase + c0 + tm*16 + mr;
            const int kd = d0 + tk*32 + kc*8;
            float yv[8];
            *(float4*)&yv[0] = *(const float4*)&sY[tm*16 + mr][tk*32 + kc*8];
            *(float4*)&yv[4] = *(const float4*)&sY[tm*16 + mr][tk*32 + kc*8 + 4];
            float zv[8];
            *(float4*)&zv[0] = *(const float4*)(xz + (size_t)m*(2*NDI) + NDI + kd);
            *(float4*)&zv[4] = *(const float4*)(xz + (size_t)m*(2*NDI) + NDI + kd + 4);
#pragma unroll
            for (int i = 0; i < 8; ++i)
                yv[i] *= zv[i] / (1.f + __expf(-zv[i]));
            short8 h8, l8; cvt8(yv, h8, l8);
            const size_t off = ((size_t)(m>>4)*16 + (kd>>5))*512 + ln2*8;
            *(short8*)(Yh + off) = h8;
            *(short8*)(Yl + off) = l8;
        }
        __syncthreads();
    }
}

// ---------------------------------------------------------------------------
__global__ __launch_bounds__(64) void score_k(
    const float* __restrict__ t1, const float* __restrict__ w2,
    float* __restrict__ sout)
{
    const int m = blockIdx.x;
    const int lane = threadIdx.x;
    float v = t1[(size_t)m*NH + lane]*w2[lane]
            + t1[(size_t)m*NH + 64 + lane]*w2[64 + lane];
#pragma unroll
    for (int o = 32; o; o >>= 1) v += __shfl_xor(v, o);
    if (lane == 0) sout[m] = v;
}

__global__ __launch_bounds__(256) void pool_k(
    const float* __restrict__ sbuf, const float* __restrict__ u,
    const int* __restrict__ lengths, float* __restrict__ ctx)
{
    __shared__ float al[NT];
    __shared__ float red[256];
    const int b = blockIdx.x;
    const int tid = threadIdx.x;
    const int len = lengths[b];
    float mx = -3.4e38f;
    for (int t = tid; t < len; t += 256) mx = fmaxf(mx, sbuf[b*NT + t]);
    red[tid] = mx; __syncthreads();
    for (int o = 128; o; o >>= 1) { if (tid < o) red[tid] = fmaxf(red[tid], red[tid+o]); __syncthreads(); }
    mx = red[0];
    __syncthreads();
    float sm = 0.f;
    for (int t = tid; t < len; t += 256) {
        float e = __expf(sbuf[b*NT + t] - mx);
        al[t] = e; sm += e;
    }
    red[tid] = sm; __syncthreads();
    for (int o = 128; o; o >>= 1) { if (tid < o) red[tid] += red[tid+o]; __syncthreads(); }
    const float rZ = 1.f / red[0];
    float acc = 0.f;
    const float* up = u + (size_t)b*NT*NDM + tid;
    for (int t = 0; t < len; ++t) acc = fmaf(al[t], up[(size_t)t*NDM], acc);
    ctx[b*NDM + tid] = acc * rZ;
}

__global__ __launch_bounds__(64) void head_k(
    const float* __restrict__ ctx, const float* __restrict__ hw,
    const float* __restrict__ hb, float* __restrict__ o)
{
    const int b = blockIdx.x;
    const int lane = threadIdx.x;
    const float4 c4 = *(const float4*)(ctx + b*NDM + lane*4);
#pragma unroll
    for (int c = 0; c < NNC; ++c) {
        const float4 w4 = *(const float4*)(hw + c*NDM + lane*4);
        float v = c4.x*w4.x + c4.y*w4.y + c4.z*w4.z + c4.w*w4.w;
#pragma unroll
        for (int off = 32; off; off >>= 1) v += __shfl_xor(v, off);
        if (lane == 0) o[b*NNC + c] = v + hb[c];
    }
}

// ---------------------------------------------------------------------------
extern "C" void kernel_launch(void* const* d_in, const int* in_sizes, int n_in,
                              void* d_out, int out_size, void* d_ws, size_t ws_size,
                              hipStream_t stream)
{
    (void)in_sizes; (void)n_in; (void)out_size; (void)ws_size;
    const float* x         = (const float*)d_in[0];
    const int*   lengths   = (const int*)  d_in[1];
    const float* tin_gamma = (const float*)d_in[2];
    const float* tin_beta  = (const float*)d_in[3];
    const float* proj_w    = (const float*)d_in[4];
    const float* proj_b    = (const float*)d_in[5];
    const float* ln_g      = (const float*)d_in[6];
    const float* ln_b      = (const float*)d_in[7];
    const float* in_proj_w = (const float*)d_in[8];
    const float* conv_w    = (const float*)d_in[9];
    const float* conv_b    = (const float*)d_in[10];
    const float* x_proj_w  = (const float*)d_in[11];
    const float* dt_proj_w = (const float*)d_in[12];
    const float* dt_proj_b = (const float*)d_in[13];
    const float* A_log     = (const float*)d_in[14];
    const float* D_param   = (const float*)d_in[15];
    const float* out_proj_w= (const float*)d_in[16];
    const float* out_ln_g  = (const float*)d_in[17];
    const float* out_ln_b  = (const float*)d_in[18];
    const float* res_scale = (const float*)d_in[19];
    const float* attn_w1   = (const float*)d_in[20];
    const float* attn_b1   = (const float*)d_in[21];
    const float* attn_w2   = (const float*)d_in[22];
    const float* head_w    = (const float*)d_in[23];
    const float* head_b    = (const float*)d_in[24];
    float* out = (float*)d_out;

    float* ws = (float*)d_ws;
    // fp32 buffers
    float* mean   = ws;                         // 65536
    float* rstd   = mean + 65536;               // 65536
    float* hbuf   = rstd + 65536;               // 4,194,304
    float* ubuf32 = hbuf + (size_t)NM*NDM;      // 4,194,304
    float* dbc    = ubuf32 + (size_t)NM*NDM;    // 786,432
    float* t1     = dbc + (size_t)NM*48;        // 2,097,152
    float* sbuf   = t1 + (size_t)NM*NH;         // 16,384
    float* ctx    = sbuf + NM;                  // 8,192
    float* fend   = ctx + NB*NDM;
    // bf16 blocked buffers (sized in floats = elems/2)
    short* ublk_h = (short*)fend;                               // NM*NDM elems
    short* ublk_l = ublk_h + (size_t)NM*NDM;
    short* xcb_h  = ublk_l + (size_t)NM*NDM;                    // NM*NDI
    short* xcb_l  = xcb_h + (size_t)NM*NDI;
    short* yq_h   = xcb_l + (size_t)NM*NDI;                     // NM*NDI
    short* yq_l   = yq_h + (size_t)NM*NDI;
    short* pw_h   = yq_l + (size_t)NM*NDI;                      // 256*2048
    short* pw_l   = pw_h + (size_t)256*2048;
    short* iw_h   = pw_l + (size_t)256*2048;                    // 4*1024*256
    short* iw_l   = iw_h + (size_t)4*1024*256;
    short* xw_h   = iw_l + (size_t)4*1024*256;                  // 4*64*512
    short* xw_l   = xw_h + (size_t)4*64*512;
    short* ow_h   = xw_l + (size_t)4*64*512;                    // 4*256*512
    short* ow_l   = ow_h + (size_t)4*256*512;
    short* aw_h   = ow_l + (size_t)4*256*512;                   // 128*256
    short* aw_l   = aw_h + (size_t)128*256;
    // overlay region: xn_blk (prologue) then xz/xc32/dt (layer loop)
    float* over   = (float*)(aw_l + (size_t)128*256);
    short* xn_h   = (short*)over;                               // NM*ND elems
    short* xn_l   = xn_h + (size_t)NM*ND;
    float* xz     = over;                                       // NM*2*NDI
    float* xc32   = over + (size_t)NM*2*NDI;                    // NM*NDI
    float* dtb_   = xc32 + (size_t)NM*NDI;                      // NM*NDI

    const dim3 blk(256);

    // --- weight conversion (once per call) ---
    wconv_k<<<dim3(16, 8), blk, 0, stream>>>(proj_w, pw_h, pw_l, 2048, 1<<28, 1<<28);
    wconv_k<<<dim3(256, 1), blk, 0, stream>>>(in_proj_w, iw_h, iw_l, 256, 1<<28, 1<<28);
    wconv_k<<<dim3(16, 2), blk, 0, stream>>>(x_proj_w, xw_h, xw_l, 512, 64, 48);
    wconv_k<<<dim3(64, 2), blk, 0, stream>>>(out_proj_w, ow_h, ow_l, 512, 1<<28, 1<<28);
    wconv_k<<<dim3(8, 1), blk, 0, stream>>>(attn_w1, aw_h, aw_l, 256, 1<<28, 1<<28);

    // --- instance norm + proj ---
    tin_stats_k<<<dim3(NB*32), blk, 0, stream>>>(x, lengths, mean, rstd);
    tin_norm_k<<<dim3(NM/16, 8), blk, 0, stream>>>(x, lengths, mean, rstd,
        tin_gamma, tin_beta, xn_h, xn_l);
    mgemm_k<4,8,0><<<dim3(256, 2), blk, 0, stream>>>(
        xn_h, xn_l, pw_h, pw_l, proj_b, hbuf, NDM, NDM, 2048, nullptr);

    for (int l = 0; l < NL; ++l) {
        ln_blk_k<0><<<dim3(NM/16), blk, 0, stream>>>(
            hbuf, ln_g + l*NDM, ln_b + l*NDM, ublk_h, ublk_l, nullptr);
        mgemm_k<8,8,0><<<dim3(128, 8), blk, 0, stream>>>(
            ublk_h, ublk_l, iw_h + (size_t)l*1024*256, iw_l + (size_t)l*1024*256,
            nullptr, xz, 2*NDI, 2*NDI, NDM, nullptr);
        conv_blk_k<<<dim3(NM/16), blk, 0, stream>>>(
            xz, conv_w + (size_t)l*NDI*4, conv_b + (size_t)l*NDI, xc32, xcb_h, xcb_l);
        mgemm_k<4,4,0><<<dim3(256, 1), blk, 0, stream>>>(
            xcb_h, xcb_l, xw_h + (size_t)l*64*512, xw_l + (size_t)l*64*512,
            nullptr, dbc, 48, 48, 512, nullptr);
        dt_k<<<dim3(NM), blk, 0, stream>>>(
            dbc, dt_proj_w + (size_t)l*NDI*NR, dt_proj_b + (size_t)l*NDI, dtb_);
        scan_k<<<dim3(NB*8), blk, 0, stream>>>(
            dbc, dtb_, xc32, xz, A_log + (size_t)l*NDI*NDS, D_param + (size_t)l*NDI,
            yq_h, yq_l);
        mgemm_k<4,8,1><<<dim3(256, 2), blk, 0, stream>>>(
            yq_h, yq_l, ow_h + (size_t)l*256*512, ow_l + (size_t)l*256*512,
            nullptr, hbuf, NDM, NDM, 512, res_scale);
    }

    ln_blk_k<1><<<dim3(NM/16), blk, 0, stream>>>(
        hbuf, out_ln_g, out_ln_b, ublk_h, ublk_l, ubuf32);
    mgemm_k<4,8,2><<<dim3(256, 1), blk, 0, stream>>>(
        ublk_h, ublk_l, aw_h, aw_l, attn_b1, t1, NH, NH, 256, nullptr);
    score_k<<<dim3(NM), dim3(64), 0, stream>>>(t1, attn_w2, sbuf);
    pool_k<<<dim3(NB), blk, 0, stream>>>(sbuf, ubuf32, lengths, ctx);
    head_k<<<dim3(NB), dim3(64), 0, stream>>>(ctx, head_w, head_b, out);
}

// Round 4
// 1501.220 us; speedup vs baseline: 1.6679x; 1.0953x over previous
//
#include <hip/hip_runtime.h>

#define NB 32       // B
#define NT 512      // T
#define ND 2048     // D
#define NDM 256     // DM
#define NDI 512     // DI
#define NDS 16      // DS
#define NR 16       // R
#define NH 128      // H
#define NNC 8       // NC
#define NL 4        // L
#define NM (NB*NT)  // 16384 tokens

typedef __attribute__((ext_vector_type(8))) short short8;
typedef __attribute__((ext_vector_type(4))) float floatx4;

__device__ __forceinline__ unsigned short f2bf_rn(float f) {
    unsigned u = __builtin_bit_cast(unsigned, f);
    u += 0x7FFFu + ((u >> 16) & 1u);
    return (unsigned short)(u >> 16);
}
__device__ __forceinline__ void cvt8(const float* v, short8& h8, short8& l8) {
#pragma unroll
    for (int q = 0; q < 8; ++q) {
        unsigned short hb = f2bf_rn(v[q]);
        float hf = __builtin_bit_cast(float, (unsigned)hb << 16);
        h8[q] = (short)hb;
        l8[q] = (short)f2bf_rn(v[q] - hf);
    }
}
// sum over the 4 lanes of a quad (lanes differing in bits 0-1) via DPP
__device__ __forceinline__ float quad_sum(float v) {
    int i = __builtin_bit_cast(int, v);
    int j = __builtin_amdgcn_update_dpp(0, i, 0xB1, 0xF, 0xF, true); // quad xor1
    v += __builtin_bit_cast(float, j);
    i = __builtin_bit_cast(int, v);
    j = __builtin_amdgcn_update_dpp(0, i, 0x4E, 0xF, 0xF, true);     // quad xor2
    v += __builtin_bit_cast(float, j);
    return v;
}

// ---------------------------------------------------------------------------
// masked time-instance-norm statistics: mean/rstd per (b,d)
// ---------------------------------------------------------------------------
__global__ __launch_bounds__(256) void tin_stats_k(
    const float* __restrict__ x, const int* __restrict__ lengths,
    float* __restrict__ mean, float* __restrict__ rstd)
{
    __shared__ float rs_[4][64];
    __shared__ float rq_[4][64];
    const int b = blockIdx.x >> 5;
    const int d0 = (blockIdx.x & 31) << 6;
    const int dl = threadIdx.x & 63;
    const int strip = threadIdx.x >> 6;
    const int len = lengths[b];
    const int d = d0 + dl;
    float s = 0.f, q = 0.f;
    for (int t = strip; t < len; t += 4) {
        float v = x[((size_t)(b*NT + t))*ND + d];
        s += v; q += v*v;
    }
    rs_[strip][dl] = s; rq_[strip][dl] = q;
    __syncthreads();
    if (threadIdx.x < 64) {
        float S = rs_[0][dl]+rs_[1][dl]+rs_[2][dl]+rs_[3][dl];
        float Q = rq_[0][dl]+rq_[1][dl]+rq_[2][dl]+rq_[3][dl];
        float inv = 1.f / (float)(len < 1 ? 1 : len);
        float mu = S * inv;
        float var = Q * inv - mu*mu;
        mean[b*ND + d] = mu;
        rstd[b*ND + d] = rsqrtf(var + 1e-5f);
    }
}

// ---------------------------------------------------------------------------
// instnorm(x) -> blocked-fragment bf16 hi/lo (A of proj GEMM)
// ---------------------------------------------------------------------------
#define SLN 264
__global__ __launch_bounds__(256) void tin_norm_k(
    const float* __restrict__ x, const int* __restrict__ lengths,
    const float* __restrict__ mean, const float* __restrict__ rstd,
    const float* __restrict__ g, const float* __restrict__ be,
    short* __restrict__ Oh, short* __restrict__ Ol)
{
    __shared__ float sT[16][SLN];
    const int tid = threadIdx.x;
    const int row = tid >> 4, c = tid & 15;
    const int m = blockIdx.x*16 + row;
    const int b = m >> 9, t = m & (NT-1);
    const int len = lengths[b];
    const int kg0 = blockIdx.y*256 + c*16;
    if (t >= len) {
#pragma unroll
        for (int i = 0; i < 16; ++i) sT[row][c*16 + i] = 0.f;
    } else {
#pragma unroll
        for (int qq = 0; qq < 4; ++qq) {
            const int kg = kg0 + qq*4;
            float4 v = *(const float4*)(x + (size_t)m*ND + kg);
            float4 mn = *(const float4*)(mean + b*ND + kg);
            float4 rr = *(const float4*)(rstd + b*ND + kg);
            float4 gg = *(const float4*)(g + kg);
            float4 bb = *(const float4*)(be + kg);
            sT[row][c*16+qq*4+0] = (v.x-mn.x)*rr.x*gg.x + bb.x;
            sT[row][c*16+qq*4+1] = (v.y-mn.y)*rr.y*gg.y + bb.y;
            sT[row][c*16+qq*4+2] = (v.z-mn.z)*rr.z*gg.z + bb.z;
            sT[row][c*16+qq*4+3] = (v.w-mn.w)*rr.w*gg.w + bb.w;
        }
    }
    __syncthreads();
#pragma unroll
    for (int q = 0; q < 2; ++q) {
        const int slot = tid + 256*q;
        const int tile = slot >> 6, ln2 = slot & 63;
        const int mr = ln2 & 15, kc = ln2 >> 4;
        float v[8];
        *(float4*)&v[0] = *(const float4*)&sT[mr][tile*32 + kc*8];
        *(float4*)&v[4] = *(const float4*)&sT[mr][tile*32 + kc*8 + 4];
        short8 h8, l8; cvt8(v, h8, l8);
        const size_t off = ((size_t)blockIdx.x*64 + blockIdx.y*8 + tile)*512 + ln2*8;
        *(short8*)(Oh + off) = h8;
        *(short8*)(Ol + off) = l8;
    }
}

// ---------------------------------------------------------------------------
// weight converter: W[N][K] fp32 row-major -> blocked hi/lo bf16
// ---------------------------------------------------------------------------
__global__ __launch_bounds__(256) void wconv_k(
    const float* __restrict__ W, short* __restrict__ Oh, short* __restrict__ Ol,
    int K, int nmod, int nvalid)
{
    __shared__ float sT[16][SLN];
    const int tid = threadIdx.x;
    const int row = tid >> 4, c = tid & 15;
    const int n = blockIdx.x*16 + row;
    const int rr = n % nmod;
    const int kg0 = blockIdx.y*256 + c*16;
    if (rr >= nvalid) {
#pragma unroll
        for (int i = 0; i < 16; ++i) sT[row][c*16 + i] = 0.f;
    } else {
        const int src = (n/nmod)*nvalid + rr;
#pragma unroll
        for (int qq = 0; qq < 4; ++qq) {
            float4 v = *(const float4*)(W + (size_t)src*K + kg0 + qq*4);
            *(float4*)&sT[row][c*16+qq*4] = v;
        }
    }
    __syncthreads();
#pragma unroll
    for (int q = 0; q < 2; ++q) {
        const int slot = tid + 256*q;
        const int tile = slot >> 6, ln2 = slot & 63;
        const int mr = ln2 & 15, kc = ln2 >> 4;
        float v[8];
        *(float4*)&v[0] = *(const float4*)&sT[mr][tile*32 + kc*8];
        *(float4*)&v[4] = *(const float4*)&sT[mr][tile*32 + kc*8 + 4];
        short8 h8, l8; cvt8(v, h8, l8);
        const size_t off = ((size_t)blockIdx.x*(K>>5) + blockIdx.y*8 + tile)*512 + ln2*8;
        *(short8*)(Oh + off) = h8;
        *(short8*)(Ol + off) = l8;
    }
}

// ---------------------------------------------------------------------------
// Split-bf16 MFMA GEMM on pre-blocked operands.
// ---------------------------------------------------------------------------
template<int MSUB, int NSUB, int EPI>
__global__ __launch_bounds__(256) void mgemm_k(
    const short* __restrict__ Ah, const short* __restrict__ Al,
    const short* __restrict__ Bh, const short* __restrict__ Bl,
    const float* __restrict__ bias, float* __restrict__ C,
    int ldc, int Nvalid, int K, const float* __restrict__ rsp)
{
    __shared__ __align__(16) short lds[(MSUB+NSUB)*1024];
    short* As_h = lds;
    short* As_l = lds + MSUB*512;
    short* Bs_h = lds + MSUB*1024;
    short* Bs_l = lds + MSUB*1024 + NSUB*512;
    const int tid = threadIdx.x, lane = tid & 63, w = tid >> 6;
    const int m0t = blockIdx.x * MSUB;
    const int n0t = blockIdx.y * NSUB;
    const int Ktiles = K >> 5;
    constexpr int MI = MSUB/2, NI = NSUB/2;
    constexpr int ASG = MSUB/4, BSG = NSUB/4;
    const int wm = w >> 1, wn = w & 1;

    floatx4 acc[MI][NI] = {};
    short8 rah[ASG], ral[ASG], rbh[BSG], rbl[BSG];

#pragma unroll
    for (int u = 0; u < ASG; ++u) {
        const size_t off = ((size_t)(m0t + w*ASG + u)*Ktiles)*512 + lane*8;
        rah[u] = *(const short8*)(Ah + off); ral[u] = *(const short8*)(Al + off);
    }
#pragma unroll
    for (int u = 0; u < BSG; ++u) {
        const size_t off = ((size_t)(n0t + w*BSG + u)*Ktiles)*512 + lane*8;
        rbh[u] = *(const short8*)(Bh + off); rbl[u] = *(const short8*)(Bl + off);
    }

    for (int kb = 0; kb < Ktiles; ++kb) {
        __syncthreads();
#pragma unroll
        for (int u = 0; u < ASG; ++u) {
            const int sub = w*ASG + u;
            *(short8*)&As_h[sub*512 + lane*8] = rah[u];
            *(short8*)&As_l[sub*512 + lane*8] = ral[u];
        }
#pragma unroll
        for (int u = 0; u < BSG; ++u) {
            const int sub = w*BSG + u;
            *(short8*)&Bs_h[sub*512 + lane*8] = rbh[u];
            *(short8*)&Bs_l[sub*512 + lane*8] = rbl[u];
        }
        __syncthreads();
        if (kb + 1 < Ktiles) {
#pragma unroll
            for (int u = 0; u < ASG; ++u) {
                const size_t off = ((size_t)(m0t + w*ASG + u)*Ktiles + kb + 1)*512 + lane*8;
                rah[u] = *(const short8*)(Ah + off); ral[u] = *(const short8*)(Al + off);
            }
#pragma unroll
            for (int u = 0; u < BSG; ++u) {
                const size_t off = ((size_t)(n0t + w*BSG + u)*Ktiles + kb + 1)*512 + lane*8;
                rbh[u] = *(const short8*)(Bh + off); rbl[u] = *(const short8*)(Bl + off);
            }
        }
        short8 fah[MI], fal[MI], fbh[NI], fbl[NI];
#pragma unroll
        for (int i = 0; i < MI; ++i) {
            const int sub = wm*MI + i;
            fah[i] = *(const short8*)&As_h[sub*512 + lane*8];
            fal[i] = *(const short8*)&As_l[sub*512 + lane*8];
        }
#pragma unroll
        for (int j = 0; j < NI; ++j) {
            const int sub = wn*NI + j;
            fbh[j] = *(const short8*)&Bs_h[sub*512 + lane*8];
            fbl[j] = *(const short8*)&Bs_l[sub*512 + lane*8];
        }
#pragma unroll
        for (int i = 0; i < MI; ++i)
#pragma unroll
            for (int j = 0; j < NI; ++j) {
                acc[i][j] = __builtin_amdgcn_mfma_f32_16x16x32_bf16(fah[i], fbh[j], acc[i][j], 0, 0, 0);
                acc[i][j] = __builtin_amdgcn_mfma_f32_16x16x32_bf16(fah[i], fbl[j], acc[i][j], 0, 0, 0);
                acc[i][j] = __builtin_amdgcn_mfma_f32_16x16x32_bf16(fal[i], fbh[j], acc[i][j], 0, 0, 0);
            }
    }

    const float rs = (EPI == 1) ? rsp[0] : 0.f;
    const int lc = lane >> 4, col = lane & 15;
#pragma unroll
    for (int j = 0; j < NI; ++j) {
        const int n = (n0t + wn*NI + j)*16 + col;
        if (n < Nvalid) {
            const float bv = (EPI != 1 && bias) ? bias[n] : 0.f;
#pragma unroll
            for (int i = 0; i < MI; ++i) {
                const int mb = (m0t + wm*MI + i)*16 + lc*4;
#pragma unroll
                for (int r = 0; r < 4; ++r) {
                    float v = acc[i][j][r];
                    float* cp = C + (size_t)(mb + r)*ldc + n;
                    if (EPI == 0)      *cp = v + bv;
                    else if (EPI == 1) *cp = fmaf(rs, v, *cp);
                    else               *cp = tanhf(v + bv);
                }
            }
        }
    }
}

// ---------------------------------------------------------------------------
// LayerNorm over DM=256 -> blocked bf16 hi/lo (+ optional fp32 row-major)
// ---------------------------------------------------------------------------
template<int WF32>
__global__ __launch_bounds__(256) void ln_blk_k(
    const float* __restrict__ in, const float* __restrict__ g,
    const float* __restrict__ b,
    short* __restrict__ Oh, short* __restrict__ Ol, float* __restrict__ o32)
{
    __shared__ float sT[16][SLN];
    const int tid = threadIdx.x;
    const int row = tid >> 4, c = tid & 15;
    const int m = blockIdx.x*16 + row;
    float v[16];
#pragma unroll
    for (int qq = 0; qq < 4; ++qq)
        *(float4*)&v[qq*4] = *(const float4*)(in + (size_t)m*NDM + c*16 + qq*4);
    float s = 0.f, q = 0.f;
#pragma unroll
    for (int i = 0; i < 16; ++i) { s += v[i]; q += v[i]*v[i]; }
#pragma unroll
    for (int o = 8; o; o >>= 1) { s += __shfl_xor(s, o); q += __shfl_xor(q, o); }
    const float mu = s * (1.f/NDM);
    const float r = rsqrtf(q*(1.f/NDM) - mu*mu + 1e-5f);
#pragma unroll
    for (int i = 0; i < 16; ++i) {
        const int kg = c*16 + i;
        v[i] = (v[i]-mu)*r*g[kg] + b[kg];
        sT[row][kg] = v[i];
    }
    if (WF32) {
#pragma unroll
        for (int qq = 0; qq < 4; ++qq)
            *(float4*)(o32 + (size_t)m*NDM + c*16 + qq*4) = *(const float4*)&v[qq*4];
    }
    __syncthreads();
#pragma unroll
    for (int qv = 0; qv < 2; ++qv) {
        const int slot = tid + 256*qv;
        const int tile = slot >> 6, ln2 = slot & 63;
        const int mr = ln2 & 15, kc = ln2 >> 4;
        float vv[8];
        *(float4*)&vv[0] = *(const float4*)&sT[mr][tile*32 + kc*8];
        *(float4*)&vv[4] = *(const float4*)&sT[mr][tile*32 + kc*8 + 4];
        short8 h8, l8; cvt8(vv, h8, l8);
        const size_t off = ((size_t)blockIdx.x*8 + tile)*512 + ln2*8;
        *(short8*)(Oh + off) = h8;
        *(short8*)(Ol + off) = l8;
    }
}

// ---------------------------------------------------------------------------
// depthwise causal conv(4) + silu -> xc fp32 row-major AND blocked hi/lo
// ---------------------------------------------------------------------------
#define SCV 520
__global__ __launch_bounds__(256) void conv_blk_k(
    const float* __restrict__ xz, const float* __restrict__ cw,
    const float* __restrict__ cb, float* __restrict__ xc32,
    short* __restrict__ Oh, short* __restrict__ Ol)
{
    __shared__ float sT[16][SCV];
    const int tid = threadIdx.x;
    const int row = tid >> 4, cg = tid & 15;
    const int m = blockIdx.x*16 + row;
    const int t = m & (NT-1);
#pragma unroll
    for (int grp = 0; grp < 4; ++grp) {
        const int ch = cg*32 + grp*8;
        float a[8];
        *(float4*)&a[0] = *(const float4*)(cb + ch);
        *(float4*)&a[4] = *(const float4*)(cb + ch + 4);
        float4 wv[8];
#pragma unroll
        for (int i = 0; i < 8; ++i) wv[i] = *(const float4*)(cw + (ch+i)*4);
#pragma unroll
        for (int kk = 0; kk < 4; ++kk) {
            if (t - 3 + kk >= 0) {
                const float* xp = xz + (size_t)(m-3+kk)*(2*NDI) + ch;
                float xv[8];
                *(float4*)&xv[0] = *(const float4*)xp;
                *(float4*)&xv[4] = *(const float4*)(xp + 4);
                const float tap[8] = {
                    kk==0?wv[0].x:kk==1?wv[0].y:kk==2?wv[0].z:wv[0].w,
                    kk==0?wv[1].x:kk==1?wv[1].y:kk==2?wv[1].z:wv[1].w,
                    kk==0?wv[2].x:kk==1?wv[2].y:kk==2?wv[2].z:wv[2].w,
                    kk==0?wv[3].x:kk==1?wv[3].y:kk==2?wv[3].z:wv[3].w,
                    kk==0?wv[4].x:kk==1?wv[4].y:kk==2?wv[4].z:wv[4].w,
                    kk==0?wv[5].x:kk==1?wv[5].y:kk==2?wv[5].z:wv[5].w,
                    kk==0?wv[6].x:kk==1?wv[6].y:kk==2?wv[6].z:wv[6].w,
                    kk==0?wv[7].x:kk==1?wv[7].y:kk==2?wv[7].z:wv[7].w};
#pragma unroll
                for (int i = 0; i < 8; ++i) a[i] = fmaf(xv[i], tap[i], a[i]);
            }
        }
#pragma unroll
        for (int i = 0; i < 8; ++i) a[i] = a[i] / (1.f + __expf(-a[i]));
        *(float4*)&sT[row][ch] = *(const float4*)&a[0];
        *(float4*)&sT[row][ch+4] = *(const float4*)&a[4];
        *(float4*)(xc32 + (size_t)m*NDI + ch) = *(const float4*)&a[0];
        *(float4*)(xc32 + (size_t)m*NDI + ch + 4) = *(const float4*)&a[4];
    }
    __syncthreads();
#pragma unroll
    for (int q = 0; q < 4; ++q) {
        const int slot = tid + 256*q;
        const int tile = slot >> 6, ln2 = slot & 63;
        const int mr = ln2 & 15, kc = ln2 >> 4;
        float vv[8];
        *(float4*)&vv[0] = *(const float4*)&sT[mr][tile*32 + kc*8];
        *(float4*)&vv[4] = *(const float4*)&sT[mr][tile*32 + kc*8 + 4];
        short8 h8, l8; cvt8(vv, h8, l8);
        const size_t off = ((size_t)blockIdx.x*16 + tile)*512 + ln2*8;
        *(short8*)(Oh + off) = h8;
        *(short8*)(Ol + off) = l8;
    }
}

// ---------------------------------------------------------------------------
// dt[m][d] = softplus(dbc[m][0:16] . dtw[d] + dtb[d]); grid NM blocks
// ---------------------------------------------------------------------------
__global__ __launch_bounds__(256) void dt_k(
    const float* __restrict__ dbc, const float* __restrict__ dtw,
    const float* __restrict__ dtb, float* __restrict__ dt)
{
    const int m = blockIdx.x;
    const float* rsrc = dbc + (size_t)m*48;
    float rv[16];
#pragma unroll
    for (int i = 0; i < 16; ++i) rv[i] = rsrc[i];
#pragma unroll
    for (int hh = 0; hh < 2; ++hh) {
        const int d = hh*256 + threadIdx.x;
        const float* wr = dtw + d*16;
        float a = dtb[d];
#pragma unroll
        for (int i = 0; i < 16; ++i) a = fmaf(rv[i], wr[i], a);
        dt[(size_t)m*NDI + d] = (a > 20.f) ? a : log1pf(__expf(a));
    }
}

// ---------------------------------------------------------------------------
// selective scan v3: 4 states/thread, DPP quad reduction (VALU pipe),
// dt/x staged in LDS transposed [d][t] for float4-per-4-step reads,
// register double-buffered 4-step groups. block=256 (64 ch), grid NB*8.
// ---------------------------------------------------------------------------
__global__ __launch_bounds__(256) void scan_k(
    const float* __restrict__ dbc, const float* __restrict__ dtp,
    const float* __restrict__ xcp, const float* __restrict__ xz,
    const float* __restrict__ Alog, const float* __restrict__ Dp,
    short* __restrict__ Yh, short* __restrict__ Yl)
{
    __shared__ float sBC[64][32];
    __shared__ float sDt[64][68];
    __shared__ float sX[64][68];
    __shared__ float sY[64][68];
    const int tid = threadIdx.x;
    const int w = tid >> 6, lane = tid & 63;
    const int dl = lane >> 2, sg = lane & 3;
    const int b = blockIdx.x >> 3;
    const int d0 = (blockIdx.x & 7) << 6;
    const int dloc = w*16 + dl;
    const int d = d0 + dloc;
    float ar[4];
    {
        float4 al4 = *(const float4*)(Alog + d*NDS + sg*4);
        ar[0] = -__expf(al4.x); ar[1] = -__expf(al4.y);
        ar[2] = -__expf(al4.z); ar[3] = -__expf(al4.w);
    }
    const float Dpv = Dp[d];
    float hr[4] = {0.f, 0.f, 0.f, 0.f};
    const int mbase = b*NT;
    const int srow = tid >> 2, sq = (tid & 3) << 3;   // dbc staging
    const int tr = tid >> 2, qq = tid & 3;            // dt/x staging

    for (int c0 = 0; c0 < NT; c0 += 64) {
        __syncthreads();
        {   // stage B/C rows: dbc[m][16..48] -> sBC[t][0..32]
            const float* dp_ = dbc + (size_t)(mbase + c0 + srow)*48 + 16 + sq;
            *(float4*)&sBC[srow][sq]   = *(const float4*)dp_;
            *(float4*)&sBC[srow][sq+4] = *(const float4*)(dp_ + 4);
        }
        {   // stage dt/x transposed -> s[d][t]
            const float* dsrc = dtp + (size_t)(mbase + c0 + tr)*NDI + d0 + qq*16;
            const float* xsrc = xcp + (size_t)(mbase + c0 + tr)*NDI + d0 + qq*16;
#pragma unroll
            for (int i = 0; i < 4; ++i) {
                float4 dv = *(const float4*)(dsrc + i*4);
                float4 xv = *(const float4*)(xsrc + i*4);
                const int dd = qq*16 + i*4;
                sDt[dd+0][tr]=dv.x; sDt[dd+1][tr]=dv.y; sDt[dd+2][tr]=dv.z; sDt[dd+3][tr]=dv.w;
                sX[dd+0][tr]=xv.x;  sX[dd+1][tr]=xv.y;  sX[dd+2][tr]=xv.z;  sX[dd+3][tr]=xv.w;
            }
        }
        __syncthreads();
        // 16 groups x 4 steps, register double-buffered
        float4 Bt[2][4], Ct[2][4], dt4[2], x4[2];
#pragma unroll
        for (int i = 0; i < 4; ++i) {
            Bt[0][i] = *(const float4*)&sBC[i][sg*4];
            Ct[0][i] = *(const float4*)&sBC[i][16 + sg*4];
        }
        dt4[0] = *(const float4*)&sDt[dloc][0];
        x4[0]  = *(const float4*)&sX[dloc][0];
#pragma unroll
        for (int g = 0; g < 16; ++g) {
            const int cur = g & 1, nxt = cur ^ 1;
            if (g < 15) {
                const int t4 = (g+1)*4;
#pragma unroll
                for (int i = 0; i < 4; ++i) {
                    Bt[nxt][i] = *(const float4*)&sBC[t4+i][sg*4];
                    Ct[nxt][i] = *(const float4*)&sBC[t4+i][16 + sg*4];
                }
                dt4[nxt] = *(const float4*)&sDt[dloc][t4];
                x4[nxt]  = *(const float4*)&sX[dloc][t4];
            }
#pragma unroll
            for (int i = 0; i < 4; ++i) {
                const float dtv = (i==0)?dt4[cur].x:(i==1)?dt4[cur].y:(i==2)?dt4[cur].z:dt4[cur].w;
                const float xv  = (i==0)?x4[cur].x:(i==1)?x4[cur].y:(i==2)?x4[cur].z:x4[cur].w;
                const float4 Bv = Bt[cur][i];
                const float4 Cv = Ct[cur][i];
                const float dbx = dtv * xv;
                float pa0 = __expf(dtv*ar[0]);
                float pa1 = __expf(dtv*ar[1]);
                float pa2 = __expf(dtv*ar[2]);
                float pa3 = __expf(dtv*ar[3]);
                hr[0] = fmaf(pa0, hr[0], dbx*Bv.x);
                hr[1] = fmaf(pa1, hr[1], dbx*Bv.y);
                hr[2] = fmaf(pa2, hr[2], dbx*Bv.z);
                hr[3] = fmaf(pa3, hr[3], dbx*Bv.w);
                float cp = hr[0]*Cv.x;
                cp = fmaf(hr[1], Cv.y, cp);
                cp = fmaf(hr[2], Cv.z, cp);
                cp = fmaf(hr[3], Cv.w, cp);
                cp = quad_sum(cp);
                if (sg == 0) sY[g*4 + i][dloc] = fmaf(Dpv, xv, cp);
            }
        }
        __syncthreads();
        // pack chunk: y * silu(z) -> blocked bf16
#pragma unroll
        for (int q = 0; q < 2; ++q) {
            const int slot = tid + 256*q;
            const int tile = slot >> 6, ln2 = slot & 63;
            const int tm = tile >> 1, tk = tile & 1;
            const int mr = ln2 & 15, kc = ln2 >> 4;
            const int m = mbase + c0 + tm*16 + mr;
            const int kd = d0 + tk*32 + kc*8;
            float yv[8];
            *(float4*)&yv[0] = *(const float4*)&sY[tm*16 + mr][tk*32 + kc*8];
            *(float4*)&yv[4] = *(const float4*)&sY[tm*16 + mr][tk*32 + kc*8 + 4];
            float zv[8];
            *(float4*)&zv[0] = *(const float4*)(xz + (size_t)m*(2*NDI) + NDI + kd);
            *(float4*)&zv[4] = *(const float4*)(xz + (size_t)m*(2*NDI) + NDI + kd + 4);
#pragma unroll
            for (int i = 0; i < 8; ++i)
                yv[i] *= zv[i] / (1.f + __expf(-zv[i]));
            short8 h8, l8; cvt8(yv, h8, l8);
            const size_t off = ((size_t)(m>>4)*16 + (kd>>5))*512 + ln2*8;
            *(short8*)(Yh + off) = h8;
            *(short8*)(Yl + off) = l8;
        }
    }
}

// ---------------------------------------------------------------------------
__global__ __launch_bounds__(64) void score_k(
    const float* __restrict__ t1, const float* __restrict__ w2,
    float* __restrict__ sout)
{
    const int m = blockIdx.x;
    const int lane = threadIdx.x;
    float v = t1[(size_t)m*NH + lane]*w2[lane]
            + t1[(size_t)m*NH + 64 + lane]*w2[64 + lane];
#pragma unroll
    for (int o = 32; o; o >>= 1) v += __shfl_xor(v, o);
    if (lane == 0) sout[m] = v;
}

__global__ __launch_bounds__(256) void pool_k(
    const float* __restrict__ sbuf, const float* __restrict__ u,
    const int* __restrict__ lengths, float* __restrict__ ctx)
{
    __shared__ float al[NT];
    __shared__ float red[256];
    const int b = blockIdx.x;
    const int tid = threadIdx.x;
    const int len = lengths[b];
    float mx = -3.4e38f;
    for (int t = tid; t < len; t += 256) mx = fmaxf(mx, sbuf[b*NT + t]);
    red[tid] = mx; __syncthreads();
    for (int o = 128; o; o >>= 1) { if (tid < o) red[tid] = fmaxf(red[tid], red[tid+o]); __syncthreads(); }
    mx = red[0];
    __syncthreads();
    float sm = 0.f;
    for (int t = tid; t < len; t += 256) {
        float e = __expf(sbuf[b*NT + t] - mx);
        al[t] = e; sm += e;
    }
    red[tid] = sm; __syncthreads();
    for (int o = 128; o; o >>= 1) { if (tid < o) red[tid] += red[tid+o]; __syncthreads(); }
    const float rZ = 1.f / red[0];
    float acc = 0.f;
    const float* up = u + (size_t)b*NT*NDM + tid;
    for (int t = 0; t < len; ++t) acc = fmaf(al[t], up[(size_t)t*NDM], acc);
    ctx[b*NDM + tid] = acc * rZ;
}

__global__ __launch_bounds__(64) void head_k(
    const float* __restrict__ ctx, const float* __restrict__ hw,
    const float* __restrict__ hb, float* __restrict__ o)
{
    const int b = blockIdx.x;
    const int lane = threadIdx.x;
    const float4 c4 = *(const float4*)(ctx + b*NDM + lane*4);
#pragma unroll
    for (int c = 0; c < NNC; ++c) {
        const float4 w4 = *(const float4*)(hw + c*NDM + lane*4);
        float v = c4.x*w4.x + c4.y*w4.y + c4.z*w4.z + c4.w*w4.w;
#pragma unroll
        for (int off = 32; off; off >>= 1) v += __shfl_xor(v, off);
        if (lane == 0) o[b*NNC + c] = v + hb[c];
    }
}

// ---------------------------------------------------------------------------
extern "C" void kernel_launch(void* const* d_in, const int* in_sizes, int n_in,
                              void* d_out, int out_size, void* d_ws, size_t ws_size,
                              hipStream_t stream)
{
    (void)in_sizes; (void)n_in; (void)out_size; (void)ws_size;
    const float* x         = (const float*)d_in[0];
    const int*   lengths   = (const int*)  d_in[1];
    const float* tin_gamma = (const float*)d_in[2];
    const float* tin_beta  = (const float*)d_in[3];
    const float* proj_w    = (const float*)d_in[4];
    const float* proj_b    = (const float*)d_in[5];
    const float* ln_g      = (const float*)d_in[6];
    const float* ln_b      = (const float*)d_in[7];
    const float* in_proj_w = (const float*)d_in[8];
    const float* conv_w    = (const float*)d_in[9];
    const float* conv_b    = (const float*)d_in[10];
    const float* x_proj_w  = (const float*)d_in[11];
    const float* dt_proj_w = (const float*)d_in[12];
    const float* dt_proj_b = (const float*)d_in[13];
    const float* A_log     = (const float*)d_in[14];
    const float* D_param   = (const float*)d_in[15];
    const float* out_proj_w= (const float*)d_in[16];
    const float* out_ln_g  = (const float*)d_in[17];
    const float* out_ln_b  = (const float*)d_in[18];
    const float* res_scale = (const float*)d_in[19];
    const float* attn_w1   = (const float*)d_in[20];
    const float* attn_b1   = (const float*)d_in[21];
    const float* attn_w2   = (const float*)d_in[22];
    const float* head_w    = (const float*)d_in[23];
    const float* head_b    = (const float*)d_in[24];
    float* out = (float*)d_out;

    float* ws = (float*)d_ws;
    float* mean   = ws;                         // 65536
    float* rstd   = mean + 65536;               // 65536
    float* hbuf   = rstd + 65536;               // NM*NDM
    float* ubuf32 = hbuf + (size_t)NM*NDM;      // NM*NDM
    float* dbc    = ubuf32 + (size_t)NM*NDM;    // NM*48
    float* t1     = dbc + (size_t)NM*48;        // NM*NH
    float* sbuf   = t1 + (size_t)NM*NH;         // NM
    float* ctx    = sbuf + NM;                  // NB*NDM
    float* fend   = ctx + NB*NDM;
    short* ublk_h = (short*)fend;
    short* ublk_l = ublk_h + (size_t)NM*NDM;
    short* xcb_h  = ublk_l + (size_t)NM*NDM;
    short* xcb_l  = xcb_h + (size_t)NM*NDI;
    short* yq_h   = xcb_l + (size_t)NM*NDI;
    short* yq_l   = yq_h + (size_t)NM*NDI;
    short* pw_h   = yq_l + (size_t)NM*NDI;
    short* pw_l   = pw_h + (size_t)256*2048;
    short* iw_h   = pw_l + (size_t)256*2048;
    short* iw_l   = iw_h + (size_t)4*1024*256;
    short* xw_h   = iw_l + (size_t)4*1024*256;
    short* xw_l   = xw_h + (size_t)4*64*512;
    short* ow_h   = xw_l + (size_t)4*64*512;
    short* ow_l   = ow_h + (size_t)4*256*512;
    short* aw_h   = ow_l + (size_t)4*256*512;
    short* aw_l   = aw_h + (size_t)128*256;
    float* over   = (float*)(aw_l + (size_t)128*256);
    short* xn_h   = (short*)over;
    short* xn_l   = xn_h + (size_t)NM*ND;
    float* xz     = over;
    float* xc32   = over + (size_t)NM*2*NDI;
    float* dtb_   = xc32 + (size_t)NM*NDI;

    const dim3 blk(256);

    wconv_k<<<dim3(16, 8), blk, 0, stream>>>(proj_w, pw_h, pw_l, 2048, 1<<28, 1<<28);
    wconv_k<<<dim3(256, 1), blk, 0, stream>>>(in_proj_w, iw_h, iw_l, 256, 1<<28, 1<<28);
    wconv_k<<<dim3(16, 2), blk, 0, stream>>>(x_proj_w, xw_h, xw_l, 512, 64, 48);
    wconv_k<<<dim3(64, 2), blk, 0, stream>>>(out_proj_w, ow_h, ow_l, 512, 1<<28, 1<<28);
    wconv_k<<<dim3(8, 1), blk, 0, stream>>>(attn_w1, aw_h, aw_l, 256, 1<<28, 1<<28);

    tin_stats_k<<<dim3(NB*32), blk, 0, stream>>>(x, lengths, mean, rstd);
    tin_norm_k<<<dim3(NM/16, 8), blk, 0, stream>>>(x, lengths, mean, rstd,
        tin_gamma, tin_beta, xn_h, xn_l);
    mgemm_k<4,8,0><<<dim3(256, 2), blk, 0, stream>>>(
        xn_h, xn_l, pw_h, pw_l, proj_b, hbuf, NDM, NDM, 2048, nullptr);

    for (int l = 0; l < NL; ++l) {
        ln_blk_k<0><<<dim3(NM/16), blk, 0, stream>>>(
            hbuf, ln_g + l*NDM, ln_b + l*NDM, ublk_h, ublk_l, nullptr);
        mgemm_k<8,8,0><<<dim3(128, 8), blk, 0, stream>>>(
            ublk_h, ublk_l, iw_h + (size_t)l*1024*256, iw_l + (size_t)l*1024*256,
            nullptr, xz, 2*NDI, 2*NDI, NDM, nullptr);
        conv_blk_k<<<dim3(NM/16), blk, 0, stream>>>(
            xz, conv_w + (size_t)l*NDI*4, conv_b + (size_t)l*NDI, xc32, xcb_h, xcb_l);
        mgemm_k<4,4,0><<<dim3(256, 1), blk, 0, stream>>>(
            xcb_h, xcb_l, xw_h + (size_t)l*64*512, xw_l + (size_t)l*64*512,
            nullptr, dbc, 48, 48, 512, nullptr);
        dt_k<<<dim3(NM), blk, 0, stream>>>(
            dbc, dt_proj_w + (size_t)l*NDI*NR, dt_proj_b + (size_t)l*NDI, dtb_);
        scan_k<<<dim3(NB*8), blk, 0, stream>>>(
            dbc, dtb_, xc32, xz, A_log + (size_t)l*NDI*NDS, D_param + (size_t)l*NDI,
            yq_h, yq_l);
        mgemm_k<4,8,1><<<dim3(256, 2), blk, 0, stream>>>(
            yq_h, yq_l, ow_h + (size_t)l*256*512, ow_l + (size_t)l*256*512,
            nullptr, hbuf, NDM, NDM, 512, res_scale);
    }

    ln_blk_k<1><<<dim3(NM/16), blk, 0, stream>>>(
        hbuf, out_ln_g, out_ln_b, ublk_h, ublk_l, ubuf32);
    mgemm_k<4,8,2><<<dim3(256, 1), blk, 0, stream>>>(
        ublk_h, ublk_l, aw_h, aw_l, attn_b1, t1, NH, NH, 256, nullptr);
    score_k<<<dim3(NM), dim3(64), 0, stream>>>(t1, attn_w2, sbuf);
    pool_k<<<dim3(NB), blk, 0, stream>>>(sbuf, ubuf32, lengths, ctx);
    head_k<<<dim3(NB), dim3(64), 0, stream>>>(ctx, head_w, head_b, out);
}